// Round 1
// baseline (462.062 us; speedup 1.0000x reference)
//
#include <hip/hip_runtime.h>

// Problem dims (fixed): B=2, L=32, C=32, S=64, W=64, R=32, MH=32
// BL = B*L = 64, SW = S*W = 4096
//
// Pipeline (algebraically reduced from the reference):
//  hs[b,l,d,s,w]   = sum_c x[b,l,c,s,w] * (pW_re + i pW_im)[c,d]      (FFT/proj/IFFT/crop collapses; bias pb lands in cropped region -> dropped)
//  Uh[c,k,r]       = ortho-IFFT_s of U,  Bq[c,k,q] = ortho-FFT_w of V (fold the second FFT2 into U/V)
//  zq[b,l,c,r,q]   = sum_{s,w} hs * conj(Uh)[c,s,r] * Bq[c,w,q]
//  scan over l:    z_t = lamb_t * z_{t-1} + gamma_t * zq_t   (in-place)
//  h_sp[b,l,c,s,w] = sum_{r,q} z * Uh[c,s,r] * conj(Bq)[c,w,q]
//  out             = x + LN_{s,w}( EffConv3x3(re(h_sp), im(h_sp)) )   (3x3 conv + 1x1 proj pre-composed)

// ---------------------------------------------------------------- transforms
__global__ __launch_bounds__(256) void k_transforms(
    const float* __restrict__ U_re, const float* __restrict__ U_im,
    const float* __restrict__ V_re, const float* __restrict__ V_im,
    float2* __restrict__ Uh, float2* __restrict__ Bqm) {
  int gid = blockIdx.x * 256 + threadIdx.x;       // 0 .. 131071
  bool isU = gid < 65536;                          // uniform per block
  int idx = isU ? gid : gid - 65536;
  int c = idx >> 11;
  int k = (idx >> 5) & 63;
  int r = idx & 31;
  const float* Ar = isU ? U_re : V_re;
  const float* Ai = isU ? U_im : V_im;
  float sr = 0.f, si = 0.f;
  for (int n = 0; n < 64; ++n) {
    float ang = (float)((k * n) & 63) * 0.09817477042468103f;  // 2*pi/64
    float sa, ca;
    sincosf(ang, &sa, &ca);
    float ar = Ar[c * 2048 + n * 32 + r];
    float ai = Ai[c * 2048 + n * 32 + r];
    if (isU) {            // e^{+i ang}  (ortho IFFT of U)
      sr += ar * ca - ai * sa;
      si += ar * sa + ai * ca;
    } else {              // e^{-i ang}  (ortho FFT of V)
      sr += ar * ca + ai * sa;
      si += ai * ca - ar * sa;
    }
  }
  float2 res = make_float2(sr * 0.125f, si * 0.125f);  // 1/sqrt(64)
  if (isU) Uh[idx] = res; else Bqm[idx] = res;
}

// ------------------------------------------------------- effective conv wts
__global__ __launch_bounds__(256) void k_weff(
    const float* __restrict__ projc_w, const float* __restrict__ projc_b,
    const float* __restrict__ convr_w, const float* __restrict__ convr_b,
    const float* __restrict__ convi_w, const float* __restrict__ convi_b,
    float* __restrict__ Wr, float* __restrict__ Wi, float* __restrict__ beff) {
  int gid = blockIdx.x * 256 + threadIdx.x;
  if (gid < 9216) {                     // [co][ci][tap] = co*288 + ci*9 + tap
    int co = gid / 288, rem = gid % 288;
    float sr = 0.f, si = 0.f;
    for (int m = 0; m < 32; ++m) {
      sr += projc_w[co * 64 + m]      * convr_w[m * 288 + rem];
      si += projc_w[co * 64 + 32 + m] * convi_w[m * 288 + rem];
    }
    Wr[gid] = sr; Wi[gid] = si;
  }
  if (gid < 32) {
    float s = projc_b[gid];
    for (int m = 0; m < 32; ++m)
      s += projc_w[gid * 64 + m] * convr_b[m] + projc_w[gid * 64 + 32 + m] * convi_b[m];
    beff[gid] = s;
  }
}

// ------------------------------------------------------------------ context
__global__ __launch_bounds__(256) void k_ctx(const float* __restrict__ x,
                                             float* __restrict__ ctx) {
  int blc = blockIdx.x;                 // 0..2047  = (b*L+l)*C + c
  const float* p = x + (size_t)blc * 4096;
  float s = 0.f;
  for (int i = threadIdx.x; i < 4096; i += 256) s += p[i];
  for (int o = 32; o > 0; o >>= 1) s += __shfl_down(s, o, 64);
  __shared__ float wsum[4];
  if ((threadIdx.x & 63) == 0) wsum[threadIdx.x >> 6] = s;
  __syncthreads();
  if (threadIdx.x == 0)
    ctx[blc] = (wsum[0] + wsum[1] + wsum[2] + wsum[3]) * (1.f / 4096.f);
}

// ------------------------------------------------------- MLP + lambda/gamma
__global__ __launch_bounds__(1024) void k_mlp(
    const float* __restrict__ ctx, const float* __restrict__ listT,
    const float* __restrict__ plb, const float* __restrict__ dmod,
    const float* __restrict__ W1, const float* __restrict__ b1,
    const float* __restrict__ W2, const float* __restrict__ b2,
    const float* __restrict__ fscale,
    float2* __restrict__ lam, float* __restrict__ gam) {
  int bl = blockIdx.x;                  // 0..63
  float dt = listT[bl];
  __shared__ float mid_s[32];
  int tid = threadIdx.x;
  if (tid < 32) {
    float a = b1[tid];
    for (int j = 0; j < 32; ++j) a += ctx[bl * 32 + j] * W1[j * 32 + tid];
    a += dt * W1[32 * 32 + tid];
    mid_s[tid] = tanhf(a);
  }
  __syncthreads();
  int c = tid >> 5, r = tid & 31;
  int col = (c * 32 + r) * 2;
  float m0 = b2[col], m1 = b2[col + 1];
  for (int h = 0; h < 32; ++h) {
    float mh = mid_s[h];
    m0 += mh * W2[h * 2048 + col];
    m1 += mh * W2[h * 2048 + col + 1];
  }
  float fs = fscale[0];
  float dnu = fs * tanhf(m0);
  float dth = fs * tanhf(m1);
  int cr = c * 32 + r;
  float nub = expf(plb[cr] + dmod[cr]);
  float thb = expf(plb[1024 + cr] + dmod[1024 + cr]);
  float nut = fmaxf(nub * dt + dnu, 1e-6f);
  float tht = thb * dt + dth;
  float e = expf(-nut);
  float sa, ca;
  sincosf(tht, &sa, &ca);
  float g = sqrtf(fmaxf(1.f - expf(-2.f * nut), 1e-12f));
  int o = bl * 1024 + cr;
  lam[o] = make_float2(e * ca, e * sa);
  gam[o] = g;
}

// -------------------------------------------------------------- channel mix
__global__ __launch_bounds__(256) void k_mix(const float* __restrict__ x,
                                             const float* __restrict__ pWr,
                                             const float* __restrict__ pWi,
                                             float2* __restrict__ hs) {
  int bl = blockIdx.x >> 4;
  int p = ((blockIdx.x & 15) << 8) + threadIdx.x;   // spatial position 0..4095
  const float* xb = x + (size_t)bl * 32 * 4096 + p;
  float xv[32];
#pragma unroll
  for (int ci = 0; ci < 32; ++ci) xv[ci] = xb[ci * 4096];
  float2* ho = hs + (size_t)bl * 32 * 4096 + p;
  for (int d = 0; d < 32; ++d) {
    float ar = 0.f, ai = 0.f;
#pragma unroll
    for (int ci = 0; ci < 32; ++ci) {
      float xc = xv[ci];
      ar += xc * pWr[ci * 32 + d];
      ai += xc * pWi[ci * 32 + d];
    }
    ho[(size_t)d * 4096] = make_float2(ar, ai);
  }
}

// ----------------------------------------------------------------- zq GEMMs
__global__ __launch_bounds__(256) void k_zq(const float2* __restrict__ hs,
                                            const float2* __restrict__ Uh,
                                            const float2* __restrict__ Bqm,
                                            float2* __restrict__ zq) {
  __shared__ float2 hs_s[64][64];   // 32 KB
  __shared__ float2 UB_s[64][33];   // 16.9 KB  (Uh, then reused for Bq)
  __shared__ float2 T_s[32][64];    // 16 KB
  const int blc = blockIdx.x;
  const int c = blc & 31;
  const int tid = threadIdx.x;
  {
    const float4* hp4 = (const float4*)(hs + (size_t)blc * 4096);
#pragma unroll
    for (int k = 0; k < 8; ++k) {
      int i = tid + k * 256;
      float4 v = hp4[i];
      int srow = i >> 5, wc = (i & 31) * 2;
      hs_s[srow][wc] = make_float2(v.x, v.y);
      hs_s[srow][wc + 1] = make_float2(v.z, v.w);
    }
    const float4* up4 = (const float4*)(Uh + c * 2048);
#pragma unroll
    for (int k = 0; k < 4; ++k) {
      int i = tid + k * 256;
      float4 v = up4[i];
      int rr = i >> 4, cc = (i & 15) * 2;
      UB_s[rr][cc] = make_float2(v.x, v.y);
      UB_s[rr][cc + 1] = make_float2(v.z, v.w);
    }
  }
  __syncthreads();
  {  // T[r][w] = sum_s conj(Uh[s][r]) * hs[s][w]   (2r x 4w per thread)
    const int wt = (tid & 15) * 4;
    const int rt = (tid >> 4) * 2;
    float tr[2][4] = {{0.f}}, ti[2][4] = {{0.f}};
    for (int s = 0; s < 64; ++s) {
      float2 uv[2];
      uv[0] = UB_s[s][rt]; uv[1] = UB_s[s][rt + 1];
      float2 hv[4];
#pragma unroll
      for (int j = 0; j < 4; ++j) hv[j] = hs_s[s][wt + j];
#pragma unroll
      for (int i = 0; i < 2; ++i)
#pragma unroll
        for (int j = 0; j < 4; ++j) {
          tr[i][j] += uv[i].x * hv[j].x + uv[i].y * hv[j].y;
          ti[i][j] += uv[i].x * hv[j].y - uv[i].y * hv[j].x;
        }
    }
#pragma unroll
    for (int i = 0; i < 2; ++i)
#pragma unroll
      for (int j = 0; j < 4; ++j)
        T_s[rt + i][wt + j] = make_float2(tr[i][j], ti[i][j]);
  }
  __syncthreads();
  {
    const float4* bp4 = (const float4*)(Bqm + c * 2048);
#pragma unroll
    for (int k = 0; k < 4; ++k) {
      int i = tid + k * 256;
      float4 v = bp4[i];
      int rr = i >> 4, cc = (i & 15) * 2;
      UB_s[rr][cc] = make_float2(v.x, v.y);
      UB_s[rr][cc + 1] = make_float2(v.z, v.w);
    }
  }
  __syncthreads();
  {  // zq[r][q] = sum_w T[r][w] * Bq[w][q]   (1r x 4q per thread)
    const int qt = (tid & 7) * 4;
    const int r = tid >> 3;
    float zr[4] = {0.f, 0.f, 0.f, 0.f}, zi[4] = {0.f, 0.f, 0.f, 0.f};
    for (int w = 0; w < 64; ++w) {
      float2 t = T_s[r][w];
      float2 bv[4];
#pragma unroll
      for (int j = 0; j < 4; ++j) bv[j] = UB_s[w][qt + j];
#pragma unroll
      for (int j = 0; j < 4; ++j) {
        zr[j] += t.x * bv[j].x - t.y * bv[j].y;
        zi[j] += t.x * bv[j].y + t.y * bv[j].x;
      }
    }
    float2* zo = zq + (size_t)blc * 1024 + r * 32 + qt;
#pragma unroll
    for (int j = 0; j < 4; ++j) zo[j] = make_float2(zr[j], zi[j]);
  }
}

// -------------------------------------------------------------- linear scan
__global__ __launch_bounds__(256) void k_scan(const float2* __restrict__ lam,
                                              const float* __restrict__ gam,
                                              float2* __restrict__ zq) {
  int idx = blockIdx.x * 256 + threadIdx.x;  // 0..65535 = b*32768 + c*1024 + r*32 + q
  int b = idx >> 15;
  int rem = idx & 32767;
  int c = rem >> 10;
  int r = (rem >> 5) & 31;
  int q = rem & 31;
  float zr = 0.f, zi = 0.f;
  for (int t = 0; t < 32; ++t) {
    int ocr = ((b * 32 + t) * 32 + c) * 32 + r;
    float2 lm = lam[ocr];
    float g = gam[ocr];
    size_t zidx = (size_t)ocr * 32 + q;
    float2 v = zq[zidx];
    float nr = lm.x * zr - lm.y * zi + g * v.x;
    float ni = lm.x * zi + lm.y * zr + g * v.y;
    zr = nr; zi = ni;
    zq[zidx] = make_float2(zr, zi);   // in-place: z_out
  }
}

// ---------------------------------------------------------- reconstruction
__global__ __launch_bounds__(256) void k_rec(const float2* __restrict__ zq,
                                             const float2* __restrict__ Uh,
                                             const float2* __restrict__ Bqm,
                                             float* __restrict__ hsr,
                                             float* __restrict__ hsi) {
  __shared__ float2 z_s[32][32];
  __shared__ float2 UB_s[64][33];   // Bq, then reused for Uh
  __shared__ float2 M_s[32][64];
  const int blc = blockIdx.x;
  const int c = blc & 31;
  const int tid = threadIdx.x;
  {
    const float4* zp4 = (const float4*)(zq + (size_t)blc * 1024);
#pragma unroll
    for (int k = 0; k < 2; ++k) {
      int i = tid + k * 256;
      float4 v = zp4[i];
      int rr = i >> 4, cc = (i & 15) * 2;
      z_s[rr][cc] = make_float2(v.x, v.y);
      z_s[rr][cc + 1] = make_float2(v.z, v.w);
    }
    const float4* bp4 = (const float4*)(Bqm + c * 2048);
#pragma unroll
    for (int k = 0; k < 4; ++k) {
      int i = tid + k * 256;
      float4 v = bp4[i];
      int rr = i >> 4, cc = (i & 15) * 2;
      UB_s[rr][cc] = make_float2(v.x, v.y);
      UB_s[rr][cc + 1] = make_float2(v.z, v.w);
    }
  }
  __syncthreads();
  {  // M[r][w] = sum_q z[r][q] * conj(Bq[w][q])
    const int wt = (tid & 15) * 4;
    const int rt = (tid >> 4) * 2;
    float mr[2][4] = {{0.f}}, mi[2][4] = {{0.f}};
    for (int q = 0; q < 32; ++q) {
      float2 zv[2];
      zv[0] = z_s[rt][q]; zv[1] = z_s[rt + 1][q];
      float2 bv[4];
#pragma unroll
      for (int j = 0; j < 4; ++j) bv[j] = UB_s[wt + j][q];
#pragma unroll
      for (int i = 0; i < 2; ++i)
#pragma unroll
        for (int j = 0; j < 4; ++j) {
          mr[i][j] += zv[i].x * bv[j].x + zv[i].y * bv[j].y;
          mi[i][j] += zv[i].y * bv[j].x - zv[i].x * bv[j].y;
        }
    }
#pragma unroll
    for (int i = 0; i < 2; ++i)
#pragma unroll
      for (int j = 0; j < 4; ++j)
        M_s[rt + i][wt + j] = make_float2(mr[i][j], mi[i][j]);
  }
  __syncthreads();
  {
    const float4* up4 = (const float4*)(Uh + c * 2048);
#pragma unroll
    for (int k = 0; k < 4; ++k) {
      int i = tid + k * 256;
      float4 v = up4[i];
      int rr = i >> 4, cc = (i & 15) * 2;
      UB_s[rr][cc] = make_float2(v.x, v.y);
      UB_s[rr][cc + 1] = make_float2(v.z, v.w);
    }
  }
  __syncthreads();
  {  // h[s][w] = sum_r Uh[s][r] * M[r][w]   (4s x 4w per thread)
    const int wt = (tid & 15) * 4;
    const int st = (tid >> 4) * 4;
    float hr_[4][4] = {{0.f}}, hi_[4][4] = {{0.f}};
    for (int r = 0; r < 32; ++r) {
      float2 uvv[4];
#pragma unroll
      for (int i = 0; i < 4; ++i) uvv[i] = UB_s[st + i][r];
      float2 mv[4];
#pragma unroll
      for (int j = 0; j < 4; ++j) mv[j] = M_s[r][wt + j];
#pragma unroll
      for (int i = 0; i < 4; ++i)
#pragma unroll
        for (int j = 0; j < 4; ++j) {
          hr_[i][j] += uvv[i].x * mv[j].x - uvv[i].y * mv[j].y;
          hi_[i][j] += uvv[i].x * mv[j].y + uvv[i].y * mv[j].x;
        }
    }
    float* pr = hsr + (size_t)blc * 4096;
    float* pi = hsi + (size_t)blc * 4096;
#pragma unroll
    for (int i = 0; i < 4; ++i) {
      *(float4*)(pr + (st + i) * 64 + wt) =
          make_float4(hr_[i][0], hr_[i][1], hr_[i][2], hr_[i][3]);
      *(float4*)(pi + (st + i) * 64 + wt) =
          make_float4(hi_[i][0], hi_[i][1], hi_[i][2], hi_[i][3]);
    }
  }
}

// --------------------------------------------------- fused conv + LN + res
__global__ __launch_bounds__(256) void k_conv_ln(
    const float* __restrict__ hsr, const float* __restrict__ hsi,
    const float* __restrict__ Wfr, const float* __restrict__ Wfi,
    const float* __restrict__ bef, const float* __restrict__ x,
    const float* __restrict__ ln_w, const float* __restrict__ ln_b,
    float* __restrict__ out) {
  __shared__ float in_s[66][68];
  __shared__ float rs[4][4], rs2[4][4];
  const int bl = blockIdx.x >> 3;            // (b*L+l)
  const int co0 = (blockIdx.x & 7) * 4;      // 4 output channels per block
  const int tid = threadIdx.x;
  const int py = (tid >> 4) * 4;
  const int px = (tid & 15) * 4;
  if (tid < 66) { in_s[0][tid] = 0.f; in_s[65][tid] = 0.f; }
  if (tid < 64) { in_s[tid + 1][0] = 0.f; in_s[tid + 1][65] = 0.f; }
  float acc[4][16];
#pragma unroll
  for (int u = 0; u < 4; ++u)
#pragma unroll
    for (int p = 0; p < 16; ++p) acc[u][p] = 0.f;

  for (int ci = 0; ci < 64; ++ci) {
    const float* plane =
        (ci < 32 ? hsr : hsi) + ((size_t)bl * 32 + (ci & 31)) * 4096;
    const float* Wbase = (ci < 32 ? Wfr : Wfi) + (ci & 31) * 9;
    __syncthreads();   // previous-plane reads done before restaging
#pragma unroll
    for (int k = 0; k < 16; ++k) {
      int i = tid + k * 256;
      in_s[(i >> 6) + 1][(i & 63) + 1] = plane[i];
    }
    __syncthreads();
    float v[6][6];
#pragma unroll
    for (int a = 0; a < 6; ++a)
#pragma unroll
      for (int bb = 0; bb < 6; ++bb) v[a][bb] = in_s[py + a][px + bb];
#pragma unroll
    for (int u = 0; u < 4; ++u) {
      const float* w9 = Wbase + (co0 + u) * 288;
      float wv[9];
#pragma unroll
      for (int t = 0; t < 9; ++t) wv[t] = w9[t];
#pragma unroll
      for (int iy = 0; iy < 4; ++iy)
#pragma unroll
        for (int ix = 0; ix < 4; ++ix) {
          float a = acc[u][iy * 4 + ix];
#pragma unroll
          for (int dy = 0; dy < 3; ++dy)
#pragma unroll
            for (int dx = 0; dx < 3; ++dx)
              a += v[iy + dy][ix + dx] * wv[dy * 3 + dx];
          acc[u][iy * 4 + ix] = a;
        }
    }
  }
  // bias + LayerNorm stats
  float sarr[4], s2arr[4];
#pragma unroll
  for (int u = 0; u < 4; ++u) {
    float bsum = bef[co0 + u];
    float s = 0.f, s2 = 0.f;
#pragma unroll
    for (int p = 0; p < 16; ++p) {
      float val = acc[u][p] + bsum;
      acc[u][p] = val;
      s += val;
      s2 += val * val;
    }
#pragma unroll
    for (int o = 32; o > 0; o >>= 1) {
      s += __shfl_down(s, o, 64);
      s2 += __shfl_down(s2, o, 64);
    }
    sarr[u] = s; s2arr[u] = s2;
  }
  if ((tid & 63) == 0) {
    int wv_ = tid >> 6;
#pragma unroll
    for (int u = 0; u < 4; ++u) { rs[wv_][u] = sarr[u]; rs2[wv_][u] = s2arr[u]; }
  }
  __syncthreads();
  float mu[4], rstd[4];
#pragma unroll
  for (int u = 0; u < 4; ++u) {
    float tot = rs[0][u] + rs[1][u] + rs[2][u] + rs[3][u];
    float tot2 = rs2[0][u] + rs2[1][u] + rs2[2][u] + rs2[3][u];
    float m = tot * (1.f / 4096.f);
    float var = tot2 * (1.f / 4096.f) - m * m;
    mu[u] = m;
    rstd[u] = rsqrtf(var + 1e-5f);
  }
#pragma unroll
  for (int u = 0; u < 4; ++u)
#pragma unroll
    for (int iy = 0; iy < 4; ++iy) {
      int pidx = (py + iy) * 64 + px;
      size_t gi = ((size_t)bl * 32 + co0 + u) * 4096 + pidx;
      float4 xv = *(const float4*)(x + gi);
      float4 lw = *(const float4*)(ln_w + pidx);
      float4 lb = *(const float4*)(ln_b + pidx);
      float4 o;
      o.x = xv.x + (acc[u][iy * 4 + 0] - mu[u]) * rstd[u] * lw.x + lb.x;
      o.y = xv.y + (acc[u][iy * 4 + 1] - mu[u]) * rstd[u] * lw.y + lb.y;
      o.z = xv.z + (acc[u][iy * 4 + 2] - mu[u]) * rstd[u] * lw.z + lb.z;
      o.w = xv.w + (acc[u][iy * 4 + 3] - mu[u]) * rstd[u] * lw.w + lb.w;
      *(float4*)(out + gi) = o;
    }
}

// ------------------------------------------------------------------- launch
extern "C" void kernel_launch(void* const* d_in, const int* in_sizes, int n_in,
                              void* d_out, int out_size, void* d_ws,
                              size_t ws_size, hipStream_t stream) {
  const float* x       = (const float*)d_in[0];
  const float* listT   = (const float*)d_in[1];
  const float* plb     = (const float*)d_in[2];
  const float* dmod    = (const float*)d_in[3];
  const float* fm_W1   = (const float*)d_in[4];
  const float* fm_b1   = (const float*)d_in[5];
  const float* fm_W2   = (const float*)d_in[6];
  const float* fm_b2   = (const float*)d_in[7];
  const float* fscale  = (const float*)d_in[8];
  const float* U_re    = (const float*)d_in[9];
  const float* U_im    = (const float*)d_in[10];
  const float* V_re    = (const float*)d_in[11];
  const float* V_im    = (const float*)d_in[12];
  const float* pW_re   = (const float*)d_in[13];
  const float* pW_im   = (const float*)d_in[14];
  // d_in[15], d_in[16] (pb_re/pb_im): provably no effect (cropped out)
  const float* convr_w = (const float*)d_in[17];
  const float* convr_b = (const float*)d_in[18];
  const float* convi_w = (const float*)d_in[19];
  const float* convi_b = (const float*)d_in[20];
  const float* projc_w = (const float*)d_in[21];
  const float* projc_b = (const float*)d_in[22];
  const float* ln_w    = (const float*)d_in[23];
  const float* ln_b    = (const float*)d_in[24];
  float* out = (float*)d_out;

  float* wsf = (float*)d_ws;
  // workspace layout (floats). hs (complex) region is reused for hsr/hsi.
  float2* hs  = (float2*)wsf;                        // 8388608 float2
  float*  hsr = wsf;                                 // alias (hs dead by then)
  float*  hsi = wsf + 8388608;
  float2* zq  = (float2*)(wsf + 16777216);           // 2097152 float2
  float2* lam = (float2*)(wsf + 20971520);           // 65536 float2
  float*  gam = wsf + 21102592;                      // 65536
  float2* Uh  = (float2*)(wsf + 21168128);           // 65536 float2
  float2* Bqm = (float2*)(wsf + 21299200);           // 65536 float2
  float*  ctx = wsf + 21430272;                      // 2048
  float*  Wfr = wsf + 21432320;                      // 9216
  float*  Wfi = wsf + 21441536;                      // 9216
  float*  bef = wsf + 21450752;                      // 32
  // total: 21,450,784 floats = 85.8 MB

  k_transforms<<<512, 256, 0, stream>>>(U_re, U_im, V_re, V_im, Uh, Bqm);
  k_weff<<<36, 256, 0, stream>>>(projc_w, projc_b, convr_w, convr_b,
                                 convi_w, convi_b, Wfr, Wfi, bef);
  k_ctx<<<2048, 256, 0, stream>>>(x, ctx);
  k_mlp<<<64, 1024, 0, stream>>>(ctx, listT, plb, dmod, fm_W1, fm_b1,
                                 fm_W2, fm_b2, fscale, lam, gam);
  k_mix<<<1024, 256, 0, stream>>>(x, pW_re, pW_im, hs);
  k_zq<<<2048, 256, 0, stream>>>(hs, Uh, Bqm, zq);
  k_scan<<<256, 256, 0, stream>>>(lam, gam, zq);
  k_rec<<<2048, 256, 0, stream>>>(zq, Uh, Bqm, hsr, hsi);
  k_conv_ln<<<512, 256, 0, stream>>>(hsr, hsi, Wfr, Wfi, bef, x, ln_w, ln_b, out);
}

// Round 2
// 397.855 us; speedup vs baseline: 1.1614x; 1.1614x over previous
//
#include <hip/hip_runtime.h>

// Dims: B=2, L=32, C=32, S=64, W=64, R=32, MH=32. BL=64, SW=4096.
//
// Reduced pipeline:
//  hs  = x ×_c (pW_re + i pW_im)          (FFT/proj/IFFT/crop collapses; pb cropped out)
//  Uh  = ortho-IFFT_s(U), Bq = ortho-FFT_w(V)
//  zq  = conj(Uh)^T hs Bq                  (per bl,c: 2 small complex GEMMs)
//  scan over l (lam, gamma)
//  hsp = Uh z conj(Bq)^T                  (packed bf16, re|im<<16)
//  out = x + LN(MFMA-conv3x3(hsp; Wtb))   (conv bias cancels in LN -> dropped)

typedef __attribute__((ext_vector_type(8))) short short8;
typedef __attribute__((ext_vector_type(4))) float floatx4;

__device__ __forceinline__ unsigned pack_bf16(float re, float im) {
  unsigned a = __float_as_uint(re), b = __float_as_uint(im);
  a = (a + 0x7FFFu + ((a >> 16) & 1u)) >> 16;
  b = (b + 0x7FFFu + ((b >> 16) & 1u)) >> 16;
  return a | (b << 16);
}

// ---------------------------------------------------- prep: transforms+weff+ctx
__global__ __launch_bounds__(256) void k_prep(
    const float* __restrict__ U_re, const float* __restrict__ U_im,
    const float* __restrict__ V_re, const float* __restrict__ V_im,
    const float* __restrict__ projc_w,
    const float* __restrict__ convr_w, const float* __restrict__ convi_w,
    const float* __restrict__ x,
    float2* __restrict__ Uh, float2* __restrict__ Bq,
    unsigned* __restrict__ Wtb, float* __restrict__ ctx) {
  const int bid = blockIdx.x;
  const int tid = threadIdx.x;
  if (bid < 512) {
    __shared__ float2 tw[64];
    if (tid < 64) {
      float sa, ca;
      sincosf((float)tid * 0.09817477042468103f, &sa, &ca);
      tw[tid] = make_float2(ca, sa);
    }
    __syncthreads();
    int gid = bid * 256 + tid;
    bool isU = gid < 65536;
    int idx = isU ? gid : gid - 65536;
    int c = idx >> 11, k = (idx >> 5) & 63, r = idx & 31;
    const float* Ar = isU ? U_re : V_re;
    const float* Ai = isU ? U_im : V_im;
    float sr = 0.f, si = 0.f;
    for (int n = 0; n < 64; ++n) {
      float2 w = tw[(k * n) & 63];
      float ar = Ar[c * 2048 + n * 32 + r];
      float ai = Ai[c * 2048 + n * 32 + r];
      if (isU) { sr += ar * w.x - ai * w.y; si += ar * w.y + ai * w.x; }
      else     { sr += ar * w.x + ai * w.y; si += ai * w.x - ar * w.y; }
    }
    float2 res = make_float2(sr * 0.125f, si * 0.125f);
    if (isU) Uh[idx] = res; else Bq[idx] = res;
  } else if (bid < 548) {
    int gid = (bid - 512) * 256 + tid;      // (co*9+tap)*32 + ci
    if (gid < 9216) {
      int co = gid / 288;
      int r2 = gid - co * 288;
      int tap = r2 >> 5, ci = r2 & 31;
      float sr = 0.f, si = 0.f;
      for (int m = 0; m < 32; ++m) {
        sr += projc_w[co * 64 + m]      * convr_w[(m * 32 + ci) * 9 + tap];
        si += projc_w[co * 64 + 32 + m] * convi_w[(m * 32 + ci) * 9 + tap];
      }
      Wtb[gid] = pack_bf16(sr, si);
    }
  } else {
    int blc = bid - 548;
    const float* p = x + (size_t)blc * 4096;
    float s = 0.f;
    for (int i = tid; i < 4096; i += 256) s += p[i];
    for (int o = 32; o > 0; o >>= 1) s += __shfl_down(s, o, 64);
    __shared__ float wsum[4];
    if ((tid & 63) == 0) wsum[tid >> 6] = s;
    __syncthreads();
    if (tid == 0)
      ctx[blc] = (wsum[0] + wsum[1] + wsum[2] + wsum[3]) * (1.f / 4096.f);
  }
}

// ------------------------------------------------------- mix (+ mlp piggyback)
__global__ __launch_bounds__(256) void k_mix_mlp(
    const float* __restrict__ x, const float* __restrict__ pWr,
    const float* __restrict__ pWi, float2* __restrict__ hs,
    const float* __restrict__ ctx, const float* __restrict__ listT,
    const float* __restrict__ plb, const float* __restrict__ dmod,
    const float* __restrict__ W1, const float* __restrict__ b1,
    const float* __restrict__ W2, const float* __restrict__ b2,
    const float* __restrict__ fscale,
    float2* __restrict__ lam, float* __restrict__ gam) {
  const int tid = threadIdx.x;
  if (blockIdx.x < 1024) {
    int bl = blockIdx.x >> 4;
    int p = ((blockIdx.x & 15) << 8) + tid;
    const float* xb = x + (size_t)bl * 32 * 4096 + p;
    float xv[32];
#pragma unroll
    for (int ci = 0; ci < 32; ++ci) xv[ci] = xb[ci * 4096];
    float2* ho = hs + (size_t)bl * 32 * 4096 + p;
    for (int d = 0; d < 32; ++d) {
      float ar = 0.f, ai = 0.f;
#pragma unroll
      for (int ci = 0; ci < 32; ++ci) {
        float xc = xv[ci];
        ar += xc * pWr[ci * 32 + d];
        ai += xc * pWi[ci * 32 + d];
      }
      ho[(size_t)d * 4096] = make_float2(ar, ai);
    }
  } else {
    int bl = blockIdx.x - 1024;
    float dt = listT[bl];
    __shared__ float mid_s[32];
    if (tid < 32) {
      float a = b1[tid];
      for (int j = 0; j < 32; ++j) a += ctx[bl * 32 + j] * W1[j * 32 + tid];
      a += dt * W1[1024 + tid];
      mid_s[tid] = tanhf(a);
    }
    __syncthreads();
    float fs = fscale[0];
#pragma unroll
    for (int u = 0; u < 4; ++u) {
      int cr = u * 256 + tid;
      int col = cr * 2;
      float m0 = b2[col], m1 = b2[col + 1];
      for (int h = 0; h < 32; ++h) {
        float mh = mid_s[h];
        float2 w2 = *(const float2*)&W2[h * 2048 + col];
        m0 += mh * w2.x;
        m1 += mh * w2.y;
      }
      float dnu = fs * tanhf(m0);
      float dth = fs * tanhf(m1);
      float nub = expf(plb[cr] + dmod[cr]);
      float thb = expf(plb[1024 + cr] + dmod[1024 + cr]);
      float nut = fmaxf(nub * dt + dnu, 1e-6f);
      float tht = thb * dt + dth;
      float e = expf(-nut);
      float sa, ca;
      sincosf(tht, &sa, &ca);
      float g = sqrtf(fmaxf(1.f - expf(-2.f * nut), 1e-12f));
      int o = bl * 1024 + cr;
      lam[o] = make_float2(e * ca, e * sa);
      gam[o] = g;
    }
  }
}

// ----------------------------------------------------------------- zq GEMMs
__global__ __launch_bounds__(256) void k_zq(const float2* __restrict__ hs,
                                            const float2* __restrict__ Uh,
                                            const float2* __restrict__ Bq,
                                            float2* __restrict__ zq) {
  __shared__ float2 hs_s[64][64];   // 32 KB, row stride 512B
  __shared__ float2 U_s[64][34];    // 17 KB, row stride 272B (16B aligned)
  __shared__ float2 T_s[32][64];    // 16 KB
  const int blc = blockIdx.x;
  const int c = blc & 31;
  const int tid = threadIdx.x;
  {
    const float4* hp4 = (const float4*)(hs + (size_t)blc * 4096);
    float4* hd4 = (float4*)&hs_s[0][0];
#pragma unroll
    for (int k = 0; k < 8; ++k) hd4[tid + k * 256] = hp4[tid + k * 256];
    const float4* up4 = (const float4*)(Uh + c * 2048);
#pragma unroll
    for (int k = 0; k < 4; ++k) {
      int i = tid + k * 256;
      *(float4*)&U_s[i >> 4][(i & 15) * 2] = up4[i];
    }
  }
  __syncthreads();
  const int wt = (tid & 15) * 4;
  const int rt = (tid >> 4) * 2;
  {  // T[r][w] = sum_s conj(U[s][r]) * h[s][w]
    float tr[2][4] = {{0.f}}, ti[2][4] = {{0.f}};
    for (int s = 0; s < 64; ++s) {
      float4 uf = *(const float4*)&U_s[s][rt];       // u0, u1
      float4 h0 = *(const float4*)&hs_s[s][wt];      // w0, w1
      float4 h1 = *(const float4*)&hs_s[s][wt + 2];  // w2, w3
      float hx[4] = {h0.x, h0.z, h1.x, h1.z};
      float hy[4] = {h0.y, h0.w, h1.y, h1.w};
      float ux[2] = {uf.x, uf.z}, uy[2] = {uf.y, uf.w};
#pragma unroll
      for (int i = 0; i < 2; ++i)
#pragma unroll
        for (int j = 0; j < 4; ++j) {
          tr[i][j] += ux[i] * hx[j] + uy[i] * hy[j];
          ti[i][j] += ux[i] * hy[j] - uy[i] * hx[j];
        }
    }
#pragma unroll
    for (int i = 0; i < 2; ++i) {
      *(float4*)&T_s[rt + i][wt]     = make_float4(tr[i][0], ti[i][0], tr[i][1], ti[i][1]);
      *(float4*)&T_s[rt + i][wt + 2] = make_float4(tr[i][2], ti[i][2], tr[i][3], ti[i][3]);
    }
  }
  __syncthreads();
  {
    const float4* bp4 = (const float4*)(Bq + c * 2048);
#pragma unroll
    for (int k = 0; k < 4; ++k) {
      int i = tid + k * 256;
      *(float4*)&U_s[i >> 4][(i & 15) * 2] = bp4[i];
    }
  }
  __syncthreads();
  {  // zq[r][q] = sum_w T[r][w] * B[w][q]
    const int qt = (tid & 7) * 4;
    const int r = tid >> 3;
    float zr[4] = {0.f, 0.f, 0.f, 0.f}, zi[4] = {0.f, 0.f, 0.f, 0.f};
    for (int w = 0; w < 64; ++w) {
      float2 t = T_s[r][w];
      float4 b0 = *(const float4*)&U_s[w][qt];
      float4 b1 = *(const float4*)&U_s[w][qt + 2];
      float bx[4] = {b0.x, b0.z, b1.x, b1.z};
      float by[4] = {b0.y, b0.w, b1.y, b1.w};
#pragma unroll
      for (int j = 0; j < 4; ++j) {
        zr[j] += t.x * bx[j] - t.y * by[j];
        zi[j] += t.x * by[j] + t.y * bx[j];
      }
    }
    float2* zo = zq + (size_t)blc * 1024 + r * 32 + qt;
    *(float4*)&zo[0] = make_float4(zr[0], zi[0], zr[1], zi[1]);
    *(float4*)&zo[2] = make_float4(zr[2], zi[2], zr[3], zi[3]);
  }
}

// -------------------------------------------------------------- linear scan
__global__ __launch_bounds__(256) void k_scan(const float2* __restrict__ lam,
                                              const float* __restrict__ gam,
                                              const float2* __restrict__ zin,
                                              float2* __restrict__ zout) {
  int idx = blockIdx.x * 256 + threadIdx.x;  // b*32768 + c*1024 + r*32 + q
  int b = idx >> 15;
  int rem = idx & 32767;
  int c = rem >> 10;
  int r = (rem >> 5) & 31;
  int q = rem & 31;
  float zr = 0.f, zi = 0.f;
#pragma unroll 4
  for (int t = 0; t < 32; ++t) {
    int ocr = ((b * 32 + t) * 32 + c) * 32 + r;
    float2 lm = lam[ocr];
    float g = gam[ocr];
    size_t zidx = (size_t)ocr * 32 + q;
    float2 v = zin[zidx];
    float nr = lm.x * zr - lm.y * zi + g * v.x;
    float ni = lm.x * zi + lm.y * zr + g * v.y;
    zr = nr; zi = ni;
    zout[zidx] = make_float2(zr, zi);
  }
}

// -------------------------------------------- reconstruction (bf16 packed out)
__global__ __launch_bounds__(256) void k_rec(const float2* __restrict__ zs,
                                             const float2* __restrict__ Uh,
                                             const float2* __restrict__ Bq,
                                             unsigned* __restrict__ hsp) {
  __shared__ float2 z_s[32][34];    // row stride 272B
  __shared__ float2 Bt_s[32][66];   // [q][w], stride 528B
  __shared__ float2 Ut_s[32][66];   // [r][s]
  __shared__ float2 M_s[32][64];
  const int blc = blockIdx.x;
  const int c = blc & 31;
  const int tid = threadIdx.x;
  {
    const float4* zp4 = (const float4*)(zs + (size_t)blc * 1024);
#pragma unroll
    for (int k = 0; k < 2; ++k) {
      int i = tid + k * 256;
      *(float4*)&z_s[i >> 4][(i & 15) * 2] = zp4[i];
    }
    const float4* bp4 = (const float4*)(Bq + c * 2048);
#pragma unroll
    for (int k = 0; k < 4; ++k) {
      int i = tid + k * 256;
      float4 v = bp4[i];
      int w = i >> 4, q0 = (i & 15) * 2;
      Bt_s[q0][w]     = make_float2(v.x, v.y);
      Bt_s[q0 + 1][w] = make_float2(v.z, v.w);
    }
    const float4* up4 = (const float4*)(Uh + c * 2048);
#pragma unroll
    for (int k = 0; k < 4; ++k) {
      int i = tid + k * 256;
      float4 v = up4[i];
      int s = i >> 4, r0 = (i & 15) * 2;
      Ut_s[r0][s]     = make_float2(v.x, v.y);
      Ut_s[r0 + 1][s] = make_float2(v.z, v.w);
    }
  }
  __syncthreads();
  const int wt = (tid & 15) * 4;
  {  // M[r][w] = sum_q z[r][q] * conj(B[w][q])
    const int rt = (tid >> 4) * 2;
    float mr[2][4] = {{0.f}}, mi[2][4] = {{0.f}};
    for (int q = 0; q < 32; ++q) {
      float2 z0 = z_s[rt][q], z1 = z_s[rt + 1][q];
      float4 b01 = *(const float4*)&Bt_s[q][wt];
      float4 b23 = *(const float4*)&Bt_s[q][wt + 2];
      float bx[4] = {b01.x, b01.z, b23.x, b23.z};
      float by[4] = {b01.y, b01.w, b23.y, b23.w};
      float zx[2] = {z0.x, z1.x}, zy[2] = {z0.y, z1.y};
#pragma unroll
      for (int i = 0; i < 2; ++i)
#pragma unroll
        for (int j = 0; j < 4; ++j) {
          mr[i][j] += zx[i] * bx[j] + zy[i] * by[j];
          mi[i][j] += zy[i] * bx[j] - zx[i] * by[j];
        }
    }
#pragma unroll
    for (int i = 0; i < 2; ++i) {
      *(float4*)&M_s[rt + i][wt]     = make_float4(mr[i][0], mi[i][0], mr[i][1], mi[i][1]);
      *(float4*)&M_s[rt + i][wt + 2] = make_float4(mr[i][2], mi[i][2], mr[i][3], mi[i][3]);
    }
  }
  __syncthreads();
  {  // h[s][w] = sum_r U[s][r] * M[r][w]
    const int st = (tid >> 4) * 4;
    float hr_[4][4] = {{0.f}}, hi_[4][4] = {{0.f}};
    for (int r = 0; r < 32; ++r) {
      float4 u01 = *(const float4*)&Ut_s[r][st];
      float4 u23 = *(const float4*)&Ut_s[r][st + 2];
      float4 m01 = *(const float4*)&M_s[r][wt];
      float4 m23 = *(const float4*)&M_s[r][wt + 2];
      float ux[4] = {u01.x, u01.z, u23.x, u23.z};
      float uy[4] = {u01.y, u01.w, u23.y, u23.w};
      float mx[4] = {m01.x, m01.z, m23.x, m23.z};
      float my[4] = {m01.y, m01.w, m23.y, m23.w};
#pragma unroll
      for (int i = 0; i < 4; ++i)
#pragma unroll
        for (int j = 0; j < 4; ++j) {
          hr_[i][j] += ux[i] * mx[j] - uy[i] * my[j];
          hi_[i][j] += ux[i] * my[j] + uy[i] * mx[j];
        }
    }
#pragma unroll
    for (int i = 0; i < 4; ++i) {
      uint4 o;
      o.x = pack_bf16(hr_[i][0], hi_[i][0]);
      o.y = pack_bf16(hr_[i][1], hi_[i][1]);
      o.z = pack_bf16(hr_[i][2], hi_[i][2]);
      o.w = pack_bf16(hr_[i][3], hi_[i][3]);
      *(uint4*)(hsp + (size_t)blc * 4096 + (st + i) * 64 + wt) = o;
    }
  }
}

// ------------------------------------------------------------ MFMA 3x3 conv
// per bl: D[4096px x 32co] = A[px x K] * W[K x co], K = 9 taps x (32ci x {re,im})
// LDS layout: [yi 0..9][xi 0..65][8 chunks swizzled][8 bf16], chunk = (k>>3)^(xi&7)
__global__ __launch_bounds__(256) void k_conv(
    const unsigned* __restrict__ hsp, const short* __restrict__ Wtb,
    float* __restrict__ convout, float2* __restrict__ stats) {
  __shared__ short lds_in[10 * 66 * 64];   // 84,480 B
  const int bl = blockIdx.x >> 3;
  const int slab = blockIdx.x & 7;
  const int y0 = slab * 8;
  const int tid = threadIdx.x;
  for (int i = tid; i < 21120; i += 256) {   // 32ci x 10y x 66x
    int ci = i / 660;
    int rem = i - ci * 660;
    int yi = rem / 66;
    int xi = rem - yi * 66;
    int y = y0 + yi - 1, xg = xi - 1;
    unsigned val = 0u;
    if ((unsigned)y < 64u && (unsigned)xg < 64u)
      val = hsp[(((size_t)bl * 32 + ci) * 64 + y) * 64 + xg];
    int slot = (ci >> 2) ^ (xi & 7);
    ((unsigned*)lds_in)[((yi * 66 + xi) * 8 + slot) * 4 + (ci & 3)] = val;
  }
  const int lane = tid & 63;
  const int wave = tid >> 6;
  const int co_t = wave >> 1;
  const int rgrp = wave & 1;
  const int co = co_t * 16 + (lane & 15);
  const int q = lane >> 4;
  short8 bfrag[18];
  {
    const short* wp = Wtb + (co * 9) * 64 + q * 8;
#pragma unroll
    for (int tap = 0; tap < 9; ++tap)
#pragma unroll
      for (int kk = 0; kk < 2; ++kk)
        bfrag[tap * 2 + kk] = *(const short8*)(wp + tap * 64 + kk * 32);
  }
  __syncthreads();
  float ssum = 0.f, ssum2 = 0.f;
  const int xb = lane & 15;
  for (int mt = 0; mt < 16; ++mt) {
    int ry = rgrp * 4 + (mt >> 2);    // row within slab
    int x0 = (mt & 3) * 16;
    floatx4 acc = {0.f, 0.f, 0.f, 0.f};
#pragma unroll
    for (int tap = 0; tap < 9; ++tap) {
      int dy = tap / 3, dx = tap - dy * 3;
      int yi = ry + dy;
      int xi = x0 + xb + dx;
      int base = (yi * 66 + xi) << 3;
#pragma unroll
      for (int kk = 0; kk < 2; ++kk) {
        int slot = ((kk << 2) | q) ^ (xi & 7);
        const short8 a = *(const short8*)&lds_in[(base + slot) << 3];
        acc = __builtin_amdgcn_mfma_f32_16x16x32_bf16(a, bfrag[tap * 2 + kk], acc, 0, 0, 0);
      }
    }
    size_t go = (((size_t)bl * 32 + co) * 64 + (y0 + ry)) * 64 + x0 + q * 4;
    *(float4*)(convout + go) = make_float4(acc[0], acc[1], acc[2], acc[3]);
    ssum  += acc[0] + acc[1] + acc[2] + acc[3];
    ssum2 += acc[0] * acc[0] + acc[1] * acc[1] + acc[2] * acc[2] + acc[3] * acc[3];
  }
  ssum  += __shfl_down(ssum, 32, 64);
  ssum2 += __shfl_down(ssum2, 32, 64);
  ssum  += __shfl_down(ssum, 16, 64);
  ssum2 += __shfl_down(ssum2, 16, 64);
  if (lane < 16)
    stats[((size_t)bl * 32 + co_t * 16 + lane) * 16 + slab * 2 + rgrp] =
        make_float2(ssum, ssum2);
}

// -------------------------------------------------------- LN + residual out
__global__ __launch_bounds__(256) void k_ln(
    const float* __restrict__ convout, const float2* __restrict__ stats,
    const float* __restrict__ x, const float* __restrict__ ln_w,
    const float* __restrict__ ln_b, float* __restrict__ out) {
  const int blc = blockIdx.x;
  const int tid = threadIdx.x;
  __shared__ float sh_mu, sh_rs;
  if (tid < 64) {
    float2 v = (tid < 16) ? stats[(size_t)blc * 16 + tid] : make_float2(0.f, 0.f);
    float s = v.x, s2 = v.y;
#pragma unroll
    for (int o = 8; o > 0; o >>= 1) {
      s += __shfl_down(s, o, 64);
      s2 += __shfl_down(s2, o, 64);
    }
    if (tid == 0) {
      float mu = s * (1.f / 4096.f);
      float var = s2 * (1.f / 4096.f) - mu * mu;
      sh_mu = mu;
      sh_rs = rsqrtf(var + 1e-5f);
    }
  }
  __syncthreads();
  float mu = sh_mu, rs = sh_rs;
  const float4* cp = (const float4*)(convout + (size_t)blc * 4096);
  const float4* xp = (const float4*)(x + (size_t)blc * 4096);
  const float4* lwp = (const float4*)ln_w;
  const float4* lbp = (const float4*)ln_b;
  float4* op = (float4*)(out + (size_t)blc * 4096);
#pragma unroll
  for (int k = 0; k < 4; ++k) {
    int i = tid + k * 256;
    float4 cv = cp[i], xv = xp[i], lw = lwp[i], lb = lbp[i];
    float4 o;
    o.x = xv.x + (cv.x - mu) * rs * lw.x + lb.x;
    o.y = xv.y + (cv.y - mu) * rs * lw.y + lb.y;
    o.z = xv.z + (cv.z - mu) * rs * lw.z + lb.z;
    o.w = xv.w + (cv.w - mu) * rs * lw.w + lb.w;
    op[i] = o;
  }
}

// ------------------------------------------------------------------- launch
extern "C" void kernel_launch(void* const* d_in, const int* in_sizes, int n_in,
                              void* d_out, int out_size, void* d_ws,
                              size_t ws_size, hipStream_t stream) {
  const float* x       = (const float*)d_in[0];
  const float* listT   = (const float*)d_in[1];
  const float* plb     = (const float*)d_in[2];
  const float* dmod    = (const float*)d_in[3];
  const float* fm_W1   = (const float*)d_in[4];
  const float* fm_b1   = (const float*)d_in[5];
  const float* fm_W2   = (const float*)d_in[6];
  const float* fm_b2   = (const float*)d_in[7];
  const float* fscale  = (const float*)d_in[8];
  const float* U_re    = (const float*)d_in[9];
  const float* U_im    = (const float*)d_in[10];
  const float* V_re    = (const float*)d_in[11];
  const float* V_im    = (const float*)d_in[12];
  const float* pW_re   = (const float*)d_in[13];
  const float* pW_im   = (const float*)d_in[14];
  // d_in[15..16] pb_re/pb_im: cropped out, no effect
  const float* convr_w = (const float*)d_in[17];
  // convr_b/convi_b/projc_b (18,20,22): constant over [S,W] -> cancel in LN
  const float* convi_w = (const float*)d_in[19];
  const float* projc_w = (const float*)d_in[21];
  const float* ln_w    = (const float*)d_in[23];
  const float* ln_b    = (const float*)d_in[24];
  float* out = (float*)d_out;

  float* wsf = (float*)d_ws;
  // R0 (16,777,216 fl): hs (mix out, fp32, full) -> later hsp (bf16 u32, first
  // half) and convout (fp32, second half). hs dead after k_zq.
  float2*   hs      = (float2*)wsf;
  unsigned* hsp     = (unsigned*)wsf;
  float*    convout = wsf + 8388608;
  float2*   zq      = (float2*)(wsf + 16777216);      // 4,194,304 fl
  size_t off = 16777216 + 4194304;
  // optional separate scan output (no-alias -> compiler can pipeline)
  float2* zs = (float2*)(wsf + off);
  size_t need_with_zs = (size_t)(off + 4194304 + 470016) * 4;
  bool sep = ws_size >= need_with_zs;
  if (sep) off += 4194304; else zs = zq;
  float2*   lam  = (float2*)(wsf + off);               // 131,072 fl
  float2*   stats = lam;                               // alias: lam dead after scan
  float*    gam  = wsf + off + 131072;                 // 65,536 fl
  float2*   Uh   = (float2*)(wsf + off + 196608);      // 131,072 fl
  float2*   Bq   = (float2*)(wsf + off + 327680);      // 131,072 fl
  float*    ctx  = wsf + off + 458752;                 // 2,048 fl
  unsigned* Wtb  = (unsigned*)(wsf + off + 460800);    // 9,216 u32
  // end: off + 470,016 fl  (no-zs total 85,766,144 B <= round-1's 85.8 MB)

  k_prep<<<2596, 256, 0, stream>>>(U_re, U_im, V_re, V_im, projc_w,
                                   convr_w, convi_w, x, Uh, Bq, Wtb, ctx);
  k_mix_mlp<<<1088, 256, 0, stream>>>(x, pW_re, pW_im, hs, ctx, listT, plb,
                                      dmod, fm_W1, fm_b1, fm_W2, fm_b2,
                                      fscale, lam, gam);
  k_zq<<<2048, 256, 0, stream>>>(hs, Uh, Bq, zq);
  k_scan<<<256, 256, 0, stream>>>(lam, gam, zq, zs);
  k_rec<<<2048, 256, 0, stream>>>(zs, Uh, Bq, hsp);
  k_conv<<<512, 256, 0, stream>>>(hsp, (const short*)Wtb, convout, stats);
  k_ln<<<2048, 256, 0, stream>>>(convout, stats, x, ln_w, ln_b, out);
}

// Round 3
// 315.163 us; speedup vs baseline: 1.4661x; 1.2624x over previous
//
#include <hip/hip_runtime.h>

// Dims: B=2, L=32, C=32, S=64, W=64, R=32, MH=32. BL=64, SW=4096.
//
// Reduced pipeline (all GEMM-shaped stages on MFMA bf16):
//  hs  = x ×_c (pW_re + i pW_im)            (packed bf16 u32 per complex)
//  Uh  = ortho-IFFT_s(U), Bq = ortho-FFT_w(V)
//  T2[s][q] = sum_w hs[s][w]·Bq[w][q]       (MFMA, K=2w+p interleaved complex)
//  zq[r][q] = sum_s conj(Uh[s][r])·T2[s][q] (MFMA)
//  scan over l (lam, gamma)                 (fp32)
//  P[s][q]  = sum_r Uh[s][r]·z[r][q]        (MFMA)
//  hsp[s][w]= sum_q P[s][q]·conj(Bq[w][q])  (MFMA, packed bf16 out)
//  out = x + LN(MFMA-conv3x3(hsp; Wtb))

typedef __attribute__((ext_vector_type(8))) short short8;
typedef __attribute__((ext_vector_type(4))) float floatx4;

__device__ __forceinline__ unsigned pack_bf16(float re, float im) {
  unsigned a = __float_as_uint(re), b = __float_as_uint(im);
  a = (a + 0x7FFFu + ((a >> 16) & 1u)) >> 16;
  b = (b + 0x7FFFu + ((b >> 16) & 1u)) >> 16;
  return a | (b << 16);
}

// ---------------------------------------------------- prep1: transforms+weff+ctx
__global__ __launch_bounds__(256) void k_prep(
    const float* __restrict__ U_re, const float* __restrict__ U_im,
    const float* __restrict__ V_re, const float* __restrict__ V_im,
    const float* __restrict__ projc_w,
    const float* __restrict__ convr_w, const float* __restrict__ convi_w,
    const float* __restrict__ x,
    float2* __restrict__ Uh, float2* __restrict__ Bq,
    unsigned* __restrict__ Wtb, float* __restrict__ ctx) {
  const int bid = blockIdx.x;
  const int tid = threadIdx.x;
  if (bid < 512) {
    __shared__ float2 tw[64];
    if (tid < 64) {
      float sa, ca;
      sincosf((float)tid * 0.09817477042468103f, &sa, &ca);
      tw[tid] = make_float2(ca, sa);
    }
    __syncthreads();
    int gid = bid * 256 + tid;
    bool isU = gid < 65536;
    int idx = isU ? gid : gid - 65536;
    int c = idx >> 11, k = (idx >> 5) & 63, r = idx & 31;
    const float* Ar = isU ? U_re : V_re;
    const float* Ai = isU ? U_im : V_im;
    float sr = 0.f, si = 0.f;
    for (int n = 0; n < 64; ++n) {
      float2 w = tw[(k * n) & 63];
      float ar = Ar[c * 2048 + n * 32 + r];
      float ai = Ai[c * 2048 + n * 32 + r];
      if (isU) { sr += ar * w.x - ai * w.y; si += ar * w.y + ai * w.x; }
      else     { sr += ar * w.x + ai * w.y; si += ai * w.x - ar * w.y; }
    }
    float2 res = make_float2(sr * 0.125f, si * 0.125f);
    if (isU) Uh[idx] = res; else Bq[idx] = res;
  } else if (bid < 548) {
    int gid = (bid - 512) * 256 + tid;      // (co*9+tap)*32 + ci
    if (gid < 9216) {
      int co = gid / 288;
      int r2 = gid - co * 288;
      int tap = r2 >> 5, ci = r2 & 31;
      float sr = 0.f, si = 0.f;
      for (int m = 0; m < 32; ++m) {
        sr += projc_w[co * 64 + m]      * convr_w[(m * 32 + ci) * 9 + tap];
        si += projc_w[co * 64 + 32 + m] * convi_w[(m * 32 + ci) * 9 + tap];
      }
      Wtb[gid] = pack_bf16(sr, si);
    }
  } else {
    int blc = bid - 548;
    const float* p = x + (size_t)blc * 4096;
    float s = 0.f;
    for (int i = tid; i < 4096; i += 256) s += p[i];
    for (int o = 32; o > 0; o >>= 1) s += __shfl_down(s, o, 64);
    __shared__ float wsum[4];
    if ((tid & 63) == 0) wsum[tid >> 6] = s;
    __syncthreads();
    if (tid == 0)
      ctx[blc] = (wsum[0] + wsum[1] + wsum[2] + wsum[3]) * (1.f / 4096.f);
  }
}

// -------------------------------- prep2: MFMA coefficient fragments from Uh/Bq
// zqA u32[((c*4+mat)*32 + m)*64 + k] : mat0 A1=(bx,-by)[q][w], mat1 A2=(by,bx)[q][w]
//                                      mat2 A3=(ux,uy)[r][s], mat3 A4=(-uy,ux)[r][s]
// recA u32[((c*2+mat)*64 + m)*32 + k]: mat0 A5=(ux,-uy)[s][r], mat1 A6=(uy,ux)[s][r]
// recB u32[((c*2+mat)*64 + n)*32 + k]: mat0 B5=(bx,by)[w][q],  mat1 B6=(-by,bx)[w][q]
__global__ __launch_bounds__(256) void k_prep2(
    const float2* __restrict__ Uh, const float2* __restrict__ Bq,
    unsigned* __restrict__ zqA, unsigned* __restrict__ recA,
    unsigned* __restrict__ recB) {
  int gid = blockIdx.x * 256 + threadIdx.x;   // < 524288
  if (gid < 262144) {
    int c = gid >> 13, mat = (gid >> 11) & 3, m = (gid >> 6) & 31, kw = gid & 63;
    unsigned pv;
    if (mat < 2) {
      float2 b = Bq[c * 2048 + kw * 32 + m];      // b[w=kw][q=m]
      pv = (mat == 0) ? pack_bf16(b.x, -b.y) : pack_bf16(b.y, b.x);
    } else {
      float2 u = Uh[c * 2048 + kw * 32 + m];      // u[s=kw][r=m]
      pv = (mat == 2) ? pack_bf16(u.x, u.y) : pack_bf16(-u.y, u.x);
    }
    zqA[gid] = pv;
  } else {
    int rid = gid - 262144;
    int c = rid >> 13, sub = rid & 8191;
    int which = sub >> 11, m = (sub >> 5) & 63, kk = sub & 31;
    if (which < 2) {
      float2 u = Uh[c * 2048 + m * 32 + kk];      // u[s=m][r=kk]
      unsigned pv = (which == 0) ? pack_bf16(u.x, -u.y) : pack_bf16(u.y, u.x);
      recA[((c * 2 + which) * 64 + m) * 32 + kk] = pv;
    } else {
      float2 b = Bq[c * 2048 + m * 32 + kk];      // b[w=m][q=kk]
      unsigned pv = (which == 2) ? pack_bf16(b.x, b.y) : pack_bf16(-b.y, b.x);
      recB[((c * 2 + (which - 2)) * 64 + m) * 32 + kk] = pv;
    }
  }
}

// ------------------------------------------------------- mix (+ mlp piggyback)
__global__ __launch_bounds__(256) void k_mix_mlp(
    const float* __restrict__ x, const float* __restrict__ pWr,
    const float* __restrict__ pWi, unsigned* __restrict__ hs,
    const float* __restrict__ ctx, const float* __restrict__ listT,
    const float* __restrict__ plb, const float* __restrict__ dmod,
    const float* __restrict__ W1, const float* __restrict__ b1,
    const float* __restrict__ W2, const float* __restrict__ b2,
    const float* __restrict__ fscale,
    float2* __restrict__ lam, float* __restrict__ gam) {
  const int tid = threadIdx.x;
  if (blockIdx.x < 1024) {
    int bl = blockIdx.x >> 4;
    int p = ((blockIdx.x & 15) << 8) + tid;
    const float* xb = x + (size_t)bl * 32 * 4096 + p;
    float xv[32];
#pragma unroll
    for (int ci = 0; ci < 32; ++ci) xv[ci] = xb[ci * 4096];
    unsigned* ho = hs + (size_t)bl * 32 * 4096 + p;
    for (int d = 0; d < 32; ++d) {
      float ar = 0.f, ai = 0.f;
#pragma unroll
      for (int ci = 0; ci < 32; ++ci) {
        float xc = xv[ci];
        ar += xc * pWr[ci * 32 + d];
        ai += xc * pWi[ci * 32 + d];
      }
      ho[(size_t)d * 4096] = pack_bf16(ar, ai);
    }
  } else {
    int bl = blockIdx.x - 1024;
    float dt = listT[bl];
    __shared__ float mid_s[32];
    if (tid < 32) {
      float a = b1[tid];
      for (int j = 0; j < 32; ++j) a += ctx[bl * 32 + j] * W1[j * 32 + tid];
      a += dt * W1[1024 + tid];
      mid_s[tid] = tanhf(a);
    }
    __syncthreads();
    float fs = fscale[0];
#pragma unroll
    for (int u = 0; u < 4; ++u) {
      int cr = u * 256 + tid;
      int col = cr * 2;
      float m0 = b2[col], m1 = b2[col + 1];
      for (int h = 0; h < 32; ++h) {
        float mh = mid_s[h];
        float2 w2 = *(const float2*)&W2[h * 2048 + col];
        m0 += mh * w2.x;
        m1 += mh * w2.y;
      }
      float dnu = fs * tanhf(m0);
      float dth = fs * tanhf(m1);
      float nub = expf(plb[cr] + dmod[cr]);
      float thb = expf(plb[1024 + cr] + dmod[1024 + cr]);
      float nut = fmaxf(nub * dt + dnu, 1e-6f);
      float tht = thb * dt + dth;
      float e = expf(-nut);
      float sa, ca;
      sincosf(tht, &sa, &ca);
      float g = sqrtf(fmaxf(1.f - expf(-2.f * nut), 1e-12f));
      int o = bl * 1024 + cr;
      lam[o] = make_float2(e * ca, e * sa);
      gam[o] = g;
    }
  }
}

// ------------------------------------------------------------ MFMA zq
// Per block (bl,c): T2[q][s] = A1/A2[32q x 128k] * Hs[128k x 64s]  (k=2w+p)
//                   zq[r][q] = A3/A4[32r x 128k] * T2[128k x 32q]  (k=2s+p)
__global__ __launch_bounds__(256) void k_zq(const unsigned* __restrict__ hs,
                                            const short* __restrict__ zqA,
                                            float2* __restrict__ zq) {
  __shared__ unsigned HsB[4096];   // [s][w-chunks xor-swizzled], 16 KB
  __shared__ unsigned T2[2048];    // [q][s-chunks xor-swizzled], 8 KB
  const int blc = blockIdx.x;
  const int c = blc & 31;
  const int tid = threadIdx.x;
  const int lane = tid & 63, wv = tid >> 6;
  const int qd = lane >> 4, ln = lane & 15;
  const int mt = wv >> 1, nth = wv & 1;
  // stage hs -> LDS (swizzled uint4)
  {
    const uint4* hp = (const uint4*)(hs + (size_t)blc * 4096);
#pragma unroll
    for (int it = 0; it < 4; ++it) {
      int i4 = tid + it * 256;                 // s = i4>>4, w4 = i4&15
      uint4 v = hp[i4];
      int s = i4 >> 4, w4 = i4 & 15;
      *(uint4*)&HsB[s * 64 + ((w4 ^ (s & 15)) << 2)] = v;
    }
  }
  // A-frags for stage-1 (A1,A2) and stage-2 (A3,A4)
  const short* zA = zqA + (size_t)c * 4 * 32 * 128;
  short8 a1[4], a2[4], a3[4], a4[4];
#pragma unroll
  for (int t = 0; t < 4; ++t) {
    int row = mt * 16 + ln;
    a1[t] = *(const short8*)(zA + (0 * 32 + row) * 128 + t * 32 + qd * 8);
    a2[t] = *(const short8*)(zA + (1 * 32 + row) * 128 + t * 32 + qd * 8);
    a3[t] = *(const short8*)(zA + (2 * 32 + row) * 128 + t * 32 + qd * 8);
    a4[t] = *(const short8*)(zA + (3 * 32 + row) * 128 + t * 32 + qd * 8);
  }
  __syncthreads();
  // stage-1: wave computes T2r,T2i for (mt, nt in {2nth, 2nth+1})
#pragma unroll
  for (int nti = 0; nti < 2; ++nti) {
    int nt = nth * 2 + nti;
    int n = nt * 16 + ln;                      // s
    floatx4 accr = {0.f, 0.f, 0.f, 0.f}, acci = {0.f, 0.f, 0.f, 0.f};
#pragma unroll
    for (int t = 0; t < 4; ++t) {
      short8 b = *(const short8*)&HsB[n * 64 + (((4 * t + qd) ^ (n & 15)) << 2)];
      accr = __builtin_amdgcn_mfma_f32_16x16x32_bf16(a1[t], b, accr, 0, 0, 0);
      acci = __builtin_amdgcn_mfma_f32_16x16x32_bf16(a2[t], b, acci, 0, 0, 0);
    }
#pragma unroll
    for (int j = 0; j < 4; ++j) {
      int q = mt * 16 + qd * 4 + j;
      int s = n;
      T2[q * 64 + (((s >> 2) ^ (q & 15)) << 2) + (s & 3)] = pack_bf16(accr[j], acci[j]);
    }
  }
  __syncthreads();
  // stage-2: wave (mt2 = r-tile, nt2 = q-tile)
  {
    const int mt2 = wv >> 1, nt2 = wv & 1;
    int n = nt2 * 16 + ln;                     // q
    floatx4 zr = {0.f, 0.f, 0.f, 0.f}, zi = {0.f, 0.f, 0.f, 0.f};
#pragma unroll
    for (int t = 0; t < 4; ++t) {
      short8 b = *(const short8*)&T2[n * 64 + (((4 * t + qd) ^ (n & 15)) << 2)];
      zr = __builtin_amdgcn_mfma_f32_16x16x32_bf16(a3[t], b, zr, 0, 0, 0);
      zi = __builtin_amdgcn_mfma_f32_16x16x32_bf16(a4[t], b, zi, 0, 0, 0);
    }
    float2* zo = zq + (size_t)blc * 1024;
#pragma unroll
    for (int j = 0; j < 4; ++j) {
      int r = mt2 * 16 + qd * 4 + j;
      zo[r * 32 + n] = make_float2(zr[j], zi[j]);
    }
  }
}

// -------------------------------------------------------------- linear scan
__global__ __launch_bounds__(256) void k_scan(const float2* __restrict__ lam,
                                              const float* __restrict__ gam,
                                              const float2* __restrict__ zin,
                                              float2* __restrict__ zout) {
  int idx = blockIdx.x * 256 + threadIdx.x;  // b*32768 + c*1024 + r*32 + q
  int b = idx >> 15;
  int rem = idx & 32767;
  int c = rem >> 10;
  int r = (rem >> 5) & 31;
  int q = rem & 31;
  float zr = 0.f, zi = 0.f;
#pragma unroll 4
  for (int t = 0; t < 32; ++t) {
    int ocr = ((b * 32 + t) * 32 + c) * 32 + r;
    float2 lm = lam[ocr];
    float g = gam[ocr];
    size_t zidx = (size_t)ocr * 32 + q;
    float2 v = zin[zidx];
    float nr = lm.x * zr - lm.y * zi + g * v.x;
    float ni = lm.x * zi + lm.y * zr + g * v.y;
    zr = nr; zi = ni;
    zout[zidx] = make_float2(zr, zi);
  }
}

// ------------------------------------------------------------ MFMA rec
// Per block: P[s][q] = A5/A6[64s x 64k] * zB[64k x 32q]   (k=2r+p)
//            hsp[s][w] = P[64s x 64k] * B5/B6[64k x 64w]  (k=2q+p)
__global__ __launch_bounds__(256) void k_rec(const float2* __restrict__ zs,
                                             const short* __restrict__ recA,
                                             const short* __restrict__ recB,
                                             unsigned* __restrict__ hsp) {
  __shared__ unsigned zB[1024];   // [q][r-chunks swizzled], 4 KB
  __shared__ unsigned P[2048];    // [s][q-chunks swizzled], 8 KB
  const int blc = blockIdx.x;
  const int c = blc & 31;
  const int tid = threadIdx.x;
  const int lane = tid & 63, wv = tid >> 6;
  const int qd = lane >> 4, ln = lane & 15;
  // stage z -> LDS bf16 transposed [q][r]
  {
    const float2* zp = zs + (size_t)blc * 1024;
#pragma unroll
    for (int it = 0; it < 4; ++it) {
      int i = tid + it * 256;                 // r = i>>5, q = i&31
      float2 v = zp[i];
      int r = i >> 5, q = i & 31;
      zB[q * 32 + (((r >> 2) ^ (q & 7)) << 2) + (r & 3)] = pack_bf16(v.x, v.y);
    }
  }
  // stage-A A-frags (A5, A6), rows s = wv*16 + ln
  const short* rA = recA + (size_t)c * 2 * 64 * 64;
  short8 a5[2], a6[2];
#pragma unroll
  for (int t = 0; t < 2; ++t) {
    int row = wv * 16 + ln;
    a5[t] = *(const short8*)(rA + (0 * 64 + row) * 64 + t * 32 + qd * 8);
    a6[t] = *(const short8*)(rA + (1 * 64 + row) * 64 + t * 32 + qd * 8);
  }
  __syncthreads();
  // stage-A: wave = s-tile (mt = wv), nt in {0,1}
#pragma unroll
  for (int nt = 0; nt < 2; ++nt) {
    int n = nt * 16 + ln;                      // q
    floatx4 pr = {0.f, 0.f, 0.f, 0.f}, pi = {0.f, 0.f, 0.f, 0.f};
#pragma unroll
    for (int t = 0; t < 2; ++t) {
      short8 b = *(const short8*)&zB[n * 32 + (((4 * t + qd) ^ (n & 7)) << 2)];
      pr = __builtin_amdgcn_mfma_f32_16x16x32_bf16(a5[t], b, pr, 0, 0, 0);
      pi = __builtin_amdgcn_mfma_f32_16x16x32_bf16(a6[t], b, pi, 0, 0, 0);
    }
#pragma unroll
    for (int j = 0; j < 4; ++j) {
      int s = wv * 16 + qd * 4 + j;
      int q = n;
      P[s * 32 + (((q >> 2) ^ (s & 7)) << 2) + (q & 3)] = pack_bf16(pr[j], pi[j]);
    }
  }
  __syncthreads();
  // stage-B: wave = s-tile (mt = wv), nt in 0..3
  const short* rB = recB + (size_t)c * 2 * 64 * 64;
  short8 pa[2];
#pragma unroll
  for (int t = 0; t < 2; ++t) {
    int row = wv * 16 + ln;                    // s
    pa[t] = *(const short8*)&P[row * 32 + (((4 * t + qd) ^ (row & 7)) << 2)];
  }
#pragma unroll
  for (int nt = 0; nt < 4; ++nt) {
    int n = nt * 16 + ln;                      // w
    floatx4 hr = {0.f, 0.f, 0.f, 0.f}, hi = {0.f, 0.f, 0.f, 0.f};
#pragma unroll
    for (int t = 0; t < 2; ++t) {
      short8 b5 = *(const short8*)(rB + (0 * 64 + n) * 64 + t * 32 + qd * 8);
      short8 b6 = *(const short8*)(rB + (1 * 64 + n) * 64 + t * 32 + qd * 8);
      hr = __builtin_amdgcn_mfma_f32_16x16x32_bf16(pa[t], b5, hr, 0, 0, 0);
      hi = __builtin_amdgcn_mfma_f32_16x16x32_bf16(pa[t], b6, hi, 0, 0, 0);
    }
    unsigned* ho = hsp + (size_t)blc * 4096;
#pragma unroll
    for (int j = 0; j < 4; ++j) {
      int s = wv * 16 + qd * 4 + j;
      ho[s * 64 + n] = pack_bf16(hr[j], hi[j]);
    }
  }
}

// ------------------------------------------------------------ MFMA 3x3 conv
__global__ __launch_bounds__(256) void k_conv(
    const unsigned* __restrict__ hsp, const short* __restrict__ Wtb,
    float* __restrict__ convout, float2* __restrict__ stats) {
  __shared__ short lds_in[10 * 66 * 64];   // 84,480 B
  const int bl = blockIdx.x >> 3;
  const int slab = blockIdx.x & 7;
  const int y0 = slab * 8;
  const int tid = threadIdx.x;
  for (int i = tid; i < 21120; i += 256) {   // 32ci x 10y x 66x
    int ci = i / 660;
    int rem = i - ci * 660;
    int yi = rem / 66;
    int xi = rem - yi * 66;
    int y = y0 + yi - 1, xg = xi - 1;
    unsigned val = 0u;
    if ((unsigned)y < 64u && (unsigned)xg < 64u)
      val = hsp[(((size_t)bl * 32 + ci) * 64 + y) * 64 + xg];
    int slot = (ci >> 2) ^ (xi & 7);
    ((unsigned*)lds_in)[((yi * 66 + xi) * 8 + slot) * 4 + (ci & 3)] = val;
  }
  const int lane = tid & 63;
  const int wave = tid >> 6;
  const int co_t = wave >> 1;
  const int rgrp = wave & 1;
  const int co = co_t * 16 + (lane & 15);
  const int q = lane >> 4;
  short8 bfrag[18];
  {
    const short* wp = Wtb + (co * 9) * 64 + q * 8;
#pragma unroll
    for (int tap = 0; tap < 9; ++tap)
#pragma unroll
      for (int kk = 0; kk < 2; ++kk)
        bfrag[tap * 2 + kk] = *(const short8*)(wp + tap * 64 + kk * 32);
  }
  __syncthreads();
  float ssum = 0.f, ssum2 = 0.f;
  const int xb = lane & 15;
  for (int mt = 0; mt < 16; ++mt) {
    int ry = rgrp * 4 + (mt >> 2);    // row within slab
    int x0 = (mt & 3) * 16;
    floatx4 acc = {0.f, 0.f, 0.f, 0.f};
#pragma unroll
    for (int tap = 0; tap < 9; ++tap) {
      int dy = tap / 3, dx = tap - dy * 3;
      int yi = ry + dy;
      int xi = x0 + xb + dx;
      int base = (yi * 66 + xi) << 3;
#pragma unroll
      for (int kk = 0; kk < 2; ++kk) {
        int slot = ((kk << 2) | q) ^ (xi & 7);
        const short8 a = *(const short8*)&lds_in[(base + slot) << 3];
        acc = __builtin_amdgcn_mfma_f32_16x16x32_bf16(a, bfrag[tap * 2 + kk], acc, 0, 0, 0);
      }
    }
    size_t go = (((size_t)bl * 32 + co) * 64 + (y0 + ry)) * 64 + x0 + q * 4;
    *(float4*)(convout + go) = make_float4(acc[0], acc[1], acc[2], acc[3]);
    ssum  += acc[0] + acc[1] + acc[2] + acc[3];
    ssum2 += acc[0] * acc[0] + acc[1] * acc[1] + acc[2] * acc[2] + acc[3] * acc[3];
  }
  ssum  += __shfl_down(ssum, 32, 64);
  ssum2 += __shfl_down(ssum2, 32, 64);
  ssum  += __shfl_down(ssum, 16, 64);
  ssum2 += __shfl_down(ssum2, 16, 64);
  if (lane < 16)
    stats[((size_t)bl * 32 + co_t * 16 + lane) * 16 + slab * 2 + rgrp] =
        make_float2(ssum, ssum2);
}

// -------------------------------------------------------- LN + residual out
__global__ __launch_bounds__(256) void k_ln(
    const float* __restrict__ convout, const float2* __restrict__ stats,
    const float* __restrict__ x, const float* __restrict__ ln_w,
    const float* __restrict__ ln_b, float* __restrict__ out) {
  const int blc = blockIdx.x;
  const int tid = threadIdx.x;
  __shared__ float sh_mu, sh_rs;
  if (tid < 64) {
    float2 v = (tid < 16) ? stats[(size_t)blc * 16 + tid] : make_float2(0.f, 0.f);
    float s = v.x, s2 = v.y;
#pragma unroll
    for (int o = 8; o > 0; o >>= 1) {
      s += __shfl_down(s, o, 64);
      s2 += __shfl_down(s2, o, 64);
    }
    if (tid == 0) {
      float mu = s * (1.f / 4096.f);
      float var = s2 * (1.f / 4096.f) - mu * mu;
      sh_mu = mu;
      sh_rs = rsqrtf(var + 1e-5f);
    }
  }
  __syncthreads();
  float mu = sh_mu, rs = sh_rs;
  const float4* cp = (const float4*)(convout + (size_t)blc * 4096);
  const float4* xp = (const float4*)(x + (size_t)blc * 4096);
  const float4* lwp = (const float4*)ln_w;
  const float4* lbp = (const float4*)ln_b;
  float4* op = (float4*)(out + (size_t)blc * 4096);
#pragma unroll
  for (int k = 0; k < 4; ++k) {
    int i = tid + k * 256;
    float4 cv = cp[i], xv = xp[i], lw = lwp[i], lb = lbp[i];
    float4 o;
    o.x = xv.x + (cv.x - mu) * rs * lw.x + lb.x;
    o.y = xv.y + (cv.y - mu) * rs * lw.y + lb.y;
    o.z = xv.z + (cv.z - mu) * rs * lw.z + lb.z;
    o.w = xv.w + (cv.w - mu) * rs * lw.w + lb.w;
    op[i] = o;
  }
}

// ------------------------------------------------------------------- launch
extern "C" void kernel_launch(void* const* d_in, const int* in_sizes, int n_in,
                              void* d_out, int out_size, void* d_ws,
                              size_t ws_size, hipStream_t stream) {
  const float* x       = (const float*)d_in[0];
  const float* listT   = (const float*)d_in[1];
  const float* plb     = (const float*)d_in[2];
  const float* dmod    = (const float*)d_in[3];
  const float* fm_W1   = (const float*)d_in[4];
  const float* fm_b1   = (const float*)d_in[5];
  const float* fm_W2   = (const float*)d_in[6];
  const float* fm_b2   = (const float*)d_in[7];
  const float* fscale  = (const float*)d_in[8];
  const float* U_re    = (const float*)d_in[9];
  const float* U_im    = (const float*)d_in[10];
  const float* V_re    = (const float*)d_in[11];
  const float* V_im    = (const float*)d_in[12];
  const float* pW_re   = (const float*)d_in[13];
  const float* pW_im   = (const float*)d_in[14];
  // d_in[15..16] pb_re/pb_im: cropped out, no effect
  const float* convr_w = (const float*)d_in[17];
  // convr_b/convi_b/projc_b (18,20,22): constant over [S,W] -> cancel in LN
  const float* convi_w = (const float*)d_in[19];
  const float* projc_w = (const float*)d_in[21];
  const float* ln_w    = (const float*)d_in[23];
  const float* ln_b    = (const float*)d_in[24];
  float* out = (float*)d_out;

  float* wsf = (float*)d_ws;
  // R0a [0, 8388608): hs (u32 packed bf16) -> later hsp (same format, alias)
  unsigned* hs  = (unsigned*)wsf;
  unsigned* hsp = (unsigned*)wsf;
  // R0b [8388608, 16777216): A-mats (2 MB, dead before conv) then convout
  float*    convout = wsf + 8388608;
  unsigned* zqAp = (unsigned*)(wsf + 8388608);        // 262144 u32
  unsigned* recAp = (unsigned*)(wsf + 8388608 + 262144); // 131072 u32
  unsigned* recBp = (unsigned*)(wsf + 8388608 + 393216); // 131072 u32
  float2*   zq  = (float2*)(wsf + 16777216);          // 4,194,304 fl
  size_t off = 16777216 + 4194304;
  float2* zs = (float2*)(wsf + off);
  size_t need_with_zs = (size_t)(off + 4194304 + 470016) * 4;
  bool sep = ws_size >= need_with_zs;
  if (sep) off += 4194304; else zs = zq;
  float2*   lam  = (float2*)(wsf + off);               // 131,072 fl
  float2*   stats = lam;                               // alias: lam dead after scan
  float*    gam  = wsf + off + 131072;                 // 65,536 fl
  float2*   Uh   = (float2*)(wsf + off + 196608);      // 131,072 fl
  float2*   Bq   = (float2*)(wsf + off + 327680);      // 131,072 fl
  float*    ctx  = wsf + off + 458752;                 // 2,048 fl
  unsigned* Wtb  = (unsigned*)(wsf + off + 460800);    // 9,216 u32

  k_prep<<<2596, 256, 0, stream>>>(U_re, U_im, V_re, V_im, projc_w,
                                   convr_w, convi_w, x, Uh, Bq, Wtb, ctx);
  k_prep2<<<2048, 256, 0, stream>>>(Uh, Bq, zqAp, recAp, recBp);
  k_mix_mlp<<<1088, 256, 0, stream>>>(x, pW_re, pW_im, hs, ctx, listT, plb,
                                      dmod, fm_W1, fm_b1, fm_W2, fm_b2,
                                      fscale, lam, gam);
  k_zq<<<2048, 256, 0, stream>>>(hs, (const short*)zqAp, zq);
  k_scan<<<256, 256, 0, stream>>>(lam, gam, zq, zs);
  k_rec<<<2048, 256, 0, stream>>>(zs, (const short*)recAp, (const short*)recBp, hsp);
  k_conv<<<512, 256, 0, stream>>>(hsp, (const short*)Wtb, convout, stats);
  k_ln<<<2048, 256, 0, stream>>>(convout, stats, x, ln_w, ln_b, out);
}

// Round 4
// 277.000 us; speedup vs baseline: 1.6681x; 1.1378x over previous
//
#include <hip/hip_runtime.h>

// Dims: B=2, L=32, C=32, S=64, W=64, R=32, MH=32. BL=64, SW=4096.
//
// Reduced pipeline (all GEMM-shaped stages on MFMA bf16):
//  hs  = x ×_c (pW_re + i pW_im)            (packed bf16 u32 per complex)
//  coefficient mats zqA/recA/recB = packed DFTs of U/V (computed in k_prep)
//  T2[s][q] = sum_w hs[s][w]·Bq[w][q]       (MFMA, K=2w+p interleaved complex)
//  zq[r][q] = sum_s conj(Uh[s][r])·T2[s][q] (MFMA)
//  scan over l (lam, gamma)                 (fp32)
//  P[s][q]  = sum_r Uh[s][r]·z[r][q]        (MFMA)
//  hsp[s][w]= sum_q P[s][q]·conj(Bq[w][q])  (MFMA, packed bf16 out)
//  out = x + LN(MFMA-conv3x3(hsp; Wtb))

typedef __attribute__((ext_vector_type(8))) short short8;
typedef __attribute__((ext_vector_type(4))) float floatx4;

__device__ __forceinline__ unsigned pack_bf16(float re, float im) {
  unsigned a = __float_as_uint(re), b = __float_as_uint(im);
  a = (a + 0x7FFFu + ((a >> 16) & 1u)) >> 16;
  b = (b + 0x7FFFu + ((b >> 16) & 1u)) >> 16;
  return a | (b << 16);
}

// ---------------------- prep: coefficient mats (direct DFT) + weff + ctx
// zqA u32[((c*4+mat)*32 + m)*64 + k] : mat0 A1=(bx,-by)[q][w], mat1 A2=(by,bx)[q][w]
//                                      mat2 A3=(ux,uy)[r][s],  mat3 A4=(-uy,ux)[r][s]
// recA u32[((c*2+v)*64 + m)*32 + k]  : v0 A5=(ux,-uy)[s][r],  v1 A6=(uy,ux)[s][r]
// recB u32[((c*2+v)*64 + n)*32 + k]  : v0 B5=(bx,by)[w][q],   v1 B6=(-by,bx)[w][q]
// where u = ortho-IFFT_s(U)[c][s][r], b = ortho-FFT_w(V)[c][w][q]
__global__ __launch_bounds__(256) void k_prep(
    const float* __restrict__ U_re, const float* __restrict__ U_im,
    const float* __restrict__ V_re, const float* __restrict__ V_im,
    const float* __restrict__ projc_w,
    const float* __restrict__ convr_w, const float* __restrict__ convi_w,
    const float* __restrict__ x,
    unsigned* __restrict__ zqA, unsigned* __restrict__ recA,
    unsigned* __restrict__ recB, unsigned* __restrict__ Wtb,
    float* __restrict__ ctx) {
  const int bid = blockIdx.x;
  const int tid = threadIdx.x;
  if (bid < 2048) {
    __shared__ float2 tw[64];
    if (tid < 64) {
      float sa, ca;
      sincosf((float)tid * 0.09817477042468103f, &sa, &ca);
      tw[tid] = make_float2(ca, sa);
    }
    __syncthreads();
    int gid = bid * 256 + tid;
    const float *Ar, *Ai;
    int knum, mode, variant;
    bool plus;
    unsigned* dst;
    int didx;
    if (gid < 262144) {                    // zqA
      int c = gid >> 13, mat = (gid >> 11) & 3, m = (gid >> 6) & 31,
          kw = gid & 63;
      knum = kw; mode = m;
      if (mat < 2) { Ar = V_re + c * 2048; Ai = V_im + c * 2048; plus = false; }
      else         { Ar = U_re + c * 2048; Ai = U_im + c * 2048; plus = true; }
      variant = mat; dst = zqA; didx = gid;
    } else {                               // recA / recB
      int rid = gid - 262144;
      int c = rid >> 13, sub = rid & 8191;
      int which = sub >> 11, mm = (sub >> 5) & 63, k2 = sub & 31;
      knum = mm; mode = k2;
      if (which < 2) {
        Ar = U_re + c * 2048; Ai = U_im + c * 2048; plus = true;
        variant = 4 + which; dst = recA;
        didx = ((c * 2 + which) * 64 + mm) * 32 + k2;
      } else {
        Ar = V_re + c * 2048; Ai = V_im + c * 2048; plus = false;
        variant = 4 + which; dst = recB;
        didx = ((c * 2 + which - 2) * 64 + mm) * 32 + k2;
      }
    }
    float sr = 0.f, si = 0.f;
    for (int n = 0; n < 64; ++n) {
      float2 w = tw[(knum * n) & 63];
      float ar = Ar[n * 32 + mode], ai = Ai[n * 32 + mode];
      if (plus) { sr += ar * w.x - ai * w.y; si += ar * w.y + ai * w.x; }
      else      { sr += ar * w.x + ai * w.y; si += ai * w.x - ar * w.y; }
    }
    sr *= 0.125f; si *= 0.125f;
    unsigned pv;
    switch (variant) {
      case 0: pv = pack_bf16(sr, -si); break;   // A1 = (bx, -by)
      case 1: pv = pack_bf16(si, sr); break;    // A2 = (by, bx)
      case 2: pv = pack_bf16(sr, si); break;    // A3 = (ux, uy)
      case 3: pv = pack_bf16(-si, sr); break;   // A4 = (-uy, ux)
      case 4: pv = pack_bf16(sr, -si); break;   // A5 = (ux, -uy)
      case 5: pv = pack_bf16(si, sr); break;    // A6 = (uy, ux)
      case 6: pv = pack_bf16(sr, si); break;    // B5 = (bx, by)
      default: pv = pack_bf16(-si, sr); break;  // B6 = (-by, bx)
    }
    dst[didx] = pv;
  } else if (bid < 2084) {                 // effective conv weights
    int gid = (bid - 2048) * 256 + tid;    // (co*9+tap)*32 + ci
    if (gid < 9216) {
      int co = gid / 288;
      int r2 = gid - co * 288;
      int tap = r2 >> 5, ci = r2 & 31;
      float sr = 0.f, si = 0.f;
      for (int m = 0; m < 32; ++m) {
        sr += projc_w[co * 64 + m]      * convr_w[(m * 32 + ci) * 9 + tap];
        si += projc_w[co * 64 + 32 + m] * convi_w[(m * 32 + ci) * 9 + tap];
      }
      Wtb[gid] = pack_bf16(sr, si);
    }
  } else {                                 // ctx = mean over S,W
    int blc = bid - 2084;
    const float* p = x + (size_t)blc * 4096;
    float s = 0.f;
    for (int i = tid; i < 4096; i += 256) s += p[i];
    for (int o = 32; o > 0; o >>= 1) s += __shfl_down(s, o, 64);
    __shared__ float wsum[4];
    if ((tid & 63) == 0) wsum[tid >> 6] = s;
    __syncthreads();
    if (tid == 0)
      ctx[blc] = (wsum[0] + wsum[1] + wsum[2] + wsum[3]) * (1.f / 4096.f);
  }
}

// ------------------------------------------------------- mix (+ mlp piggyback)
__global__ __launch_bounds__(256) void k_mix_mlp(
    const float* __restrict__ x, const float* __restrict__ pWr,
    const float* __restrict__ pWi, unsigned* __restrict__ hs,
    const float* __restrict__ ctx, const float* __restrict__ listT,
    const float* __restrict__ plb, const float* __restrict__ dmod,
    const float* __restrict__ W1, const float* __restrict__ b1,
    const float* __restrict__ W2, const float* __restrict__ b2,
    const float* __restrict__ fscale,
    float2* __restrict__ lam, float* __restrict__ gam) {
  const int tid = threadIdx.x;
  if (blockIdx.x < 1024) {
    int bl = blockIdx.x >> 4;
    int p = ((blockIdx.x & 15) << 8) + tid;
    const float* xb = x + (size_t)bl * 32 * 4096 + p;
    float xv[32];
#pragma unroll
    for (int ci = 0; ci < 32; ++ci) xv[ci] = xb[ci * 4096];
    unsigned* ho = hs + (size_t)bl * 32 * 4096 + p;
    for (int d = 0; d < 32; ++d) {
      float ar = 0.f, ai = 0.f;
#pragma unroll
      for (int ci = 0; ci < 32; ++ci) {
        float xc = xv[ci];
        ar += xc * pWr[ci * 32 + d];
        ai += xc * pWi[ci * 32 + d];
      }
      ho[(size_t)d * 4096] = pack_bf16(ar, ai);
    }
  } else {
    int bl = blockIdx.x - 1024;
    float dt = listT[bl];
    __shared__ float mid_s[32];
    if (tid < 32) {
      float a = b1[tid];
      for (int j = 0; j < 32; ++j) a += ctx[bl * 32 + j] * W1[j * 32 + tid];
      a += dt * W1[1024 + tid];
      mid_s[tid] = tanhf(a);
    }
    __syncthreads();
    float fs = fscale[0];
#pragma unroll
    for (int u = 0; u < 4; ++u) {
      int cr = u * 256 + tid;
      int col = cr * 2;
      float m0 = b2[col], m1 = b2[col + 1];
      for (int h = 0; h < 32; ++h) {
        float mh = mid_s[h];
        float2 w2 = *(const float2*)&W2[h * 2048 + col];
        m0 += mh * w2.x;
        m1 += mh * w2.y;
      }
      float dnu = fs * tanhf(m0);
      float dth = fs * tanhf(m1);
      float nub = expf(plb[cr] + dmod[cr]);
      float thb = expf(plb[1024 + cr] + dmod[1024 + cr]);
      float nut = fmaxf(nub * dt + dnu, 1e-6f);
      float tht = thb * dt + dth;
      float e = expf(-nut);
      float sa, ca;
      sincosf(tht, &sa, &ca);
      float g = sqrtf(fmaxf(1.f - expf(-2.f * nut), 1e-12f));
      int o = bl * 1024 + cr;
      lam[o] = make_float2(e * ca, e * sa);
      gam[o] = g;
    }
  }
}

// ------------------------------------------------------------ MFMA zq
__global__ __launch_bounds__(256) void k_zq(const unsigned* __restrict__ hs,
                                            const short* __restrict__ zqA,
                                            float2* __restrict__ zq) {
  __shared__ unsigned HsB[4096];   // [s][w-chunks xor-swizzled], 16 KB
  __shared__ unsigned T2[2048];    // [q][s-chunks xor-swizzled], 8 KB
  const int blc = blockIdx.x;
  const int c = blc & 31;
  const int tid = threadIdx.x;
  const int lane = tid & 63, wv = tid >> 6;
  const int qd = lane >> 4, ln = lane & 15;
  const int mt = wv >> 1, nth = wv & 1;
  {
    const uint4* hp = (const uint4*)(hs + (size_t)blc * 4096);
#pragma unroll
    for (int it = 0; it < 4; ++it) {
      int i4 = tid + it * 256;
      uint4 v = hp[i4];
      int s = i4 >> 4, w4 = i4 & 15;
      *(uint4*)&HsB[s * 64 + ((w4 ^ (s & 15)) << 2)] = v;
    }
  }
  const short* zA = zqA + (size_t)c * 4 * 32 * 128;
  short8 a1[4], a2[4], a3[4], a4[4];
#pragma unroll
  for (int t = 0; t < 4; ++t) {
    int row = mt * 16 + ln;
    a1[t] = *(const short8*)(zA + (0 * 32 + row) * 128 + t * 32 + qd * 8);
    a2[t] = *(const short8*)(zA + (1 * 32 + row) * 128 + t * 32 + qd * 8);
    a3[t] = *(const short8*)(zA + (2 * 32 + row) * 128 + t * 32 + qd * 8);
    a4[t] = *(const short8*)(zA + (3 * 32 + row) * 128 + t * 32 + qd * 8);
  }
  __syncthreads();
#pragma unroll
  for (int nti = 0; nti < 2; ++nti) {
    int nt = nth * 2 + nti;
    int n = nt * 16 + ln;
    floatx4 accr = {0.f, 0.f, 0.f, 0.f}, acci = {0.f, 0.f, 0.f, 0.f};
#pragma unroll
    for (int t = 0; t < 4; ++t) {
      short8 b = *(const short8*)&HsB[n * 64 + (((4 * t + qd) ^ (n & 15)) << 2)];
      accr = __builtin_amdgcn_mfma_f32_16x16x32_bf16(a1[t], b, accr, 0, 0, 0);
      acci = __builtin_amdgcn_mfma_f32_16x16x32_bf16(a2[t], b, acci, 0, 0, 0);
    }
#pragma unroll
    for (int j = 0; j < 4; ++j) {
      int q = mt * 16 + qd * 4 + j;
      int s = n;
      T2[q * 64 + (((s >> 2) ^ (q & 15)) << 2) + (s & 3)] = pack_bf16(accr[j], acci[j]);
    }
  }
  __syncthreads();
  {
    const int mt2 = wv >> 1, nt2 = wv & 1;
    int n = nt2 * 16 + ln;
    floatx4 zr = {0.f, 0.f, 0.f, 0.f}, zi = {0.f, 0.f, 0.f, 0.f};
#pragma unroll
    for (int t = 0; t < 4; ++t) {
      short8 b = *(const short8*)&T2[n * 64 + (((4 * t + qd) ^ (n & 15)) << 2)];
      zr = __builtin_amdgcn_mfma_f32_16x16x32_bf16(a3[t], b, zr, 0, 0, 0);
      zi = __builtin_amdgcn_mfma_f32_16x16x32_bf16(a4[t], b, zi, 0, 0, 0);
    }
    float2* zo = zq + (size_t)blc * 1024;
#pragma unroll
    for (int j = 0; j < 4; ++j) {
      int r = mt2 * 16 + qd * 4 + j;
      zo[r * 32 + n] = make_float2(zr[j], zi[j]);
    }
  }
}

// -------------------------------------------------------------- linear scan
__global__ __launch_bounds__(256) void k_scan(const float2* __restrict__ lam,
                                              const float* __restrict__ gam,
                                              const float2* __restrict__ zin,
                                              float2* __restrict__ zout) {
  int idx = blockIdx.x * 256 + threadIdx.x;
  int b = idx >> 15;
  int rem = idx & 32767;
  int c = rem >> 10;
  int r = (rem >> 5) & 31;
  int q = rem & 31;
  float zr = 0.f, zi = 0.f;
#pragma unroll 4
  for (int t = 0; t < 32; ++t) {
    int ocr = ((b * 32 + t) * 32 + c) * 32 + r;
    float2 lm = lam[ocr];
    float g = gam[ocr];
    size_t zidx = (size_t)ocr * 32 + q;
    float2 v = zin[zidx];
    float nr = lm.x * zr - lm.y * zi + g * v.x;
    float ni = lm.x * zi + lm.y * zr + g * v.y;
    zr = nr; zi = ni;
    zout[zidx] = make_float2(zr, zi);
  }
}

// ------------------------------------------------------------ MFMA rec
__global__ __launch_bounds__(256) void k_rec(const float2* __restrict__ zs,
                                             const short* __restrict__ recA,
                                             const short* __restrict__ recB,
                                             unsigned* __restrict__ hsp) {
  __shared__ unsigned zB[1024];
  __shared__ unsigned P[2048];
  const int blc = blockIdx.x;
  const int c = blc & 31;
  const int tid = threadIdx.x;
  const int lane = tid & 63, wv = tid >> 6;
  const int qd = lane >> 4, ln = lane & 15;
  {
    const float2* zp = zs + (size_t)blc * 1024;
#pragma unroll
    for (int it = 0; it < 4; ++it) {
      int i = tid + it * 256;
      float2 v = zp[i];
      int r = i >> 5, q = i & 31;
      zB[q * 32 + (((r >> 2) ^ (q & 7)) << 2) + (r & 3)] = pack_bf16(v.x, v.y);
    }
  }
  const short* rA = recA + (size_t)c * 2 * 64 * 64;
  short8 a5[2], a6[2];
#pragma unroll
  for (int t = 0; t < 2; ++t) {
    int row = wv * 16 + ln;
    a5[t] = *(const short8*)(rA + (0 * 64 + row) * 64 + t * 32 + qd * 8);
    a6[t] = *(const short8*)(rA + (1 * 64 + row) * 64 + t * 32 + qd * 8);
  }
  __syncthreads();
#pragma unroll
  for (int nt = 0; nt < 2; ++nt) {
    int n = nt * 16 + ln;
    floatx4 pr = {0.f, 0.f, 0.f, 0.f}, pi = {0.f, 0.f, 0.f, 0.f};
#pragma unroll
    for (int t = 0; t < 2; ++t) {
      short8 b = *(const short8*)&zB[n * 32 + (((4 * t + qd) ^ (n & 7)) << 2)];
      pr = __builtin_amdgcn_mfma_f32_16x16x32_bf16(a5[t], b, pr, 0, 0, 0);
      pi = __builtin_amdgcn_mfma_f32_16x16x32_bf16(a6[t], b, pi, 0, 0, 0);
    }
#pragma unroll
    for (int j = 0; j < 4; ++j) {
      int s = wv * 16 + qd * 4 + j;
      int q = n;
      P[s * 32 + (((q >> 2) ^ (s & 7)) << 2) + (q & 3)] = pack_bf16(pr[j], pi[j]);
    }
  }
  __syncthreads();
  const short* rB = recB + (size_t)c * 2 * 64 * 64;
  short8 pa[2];
#pragma unroll
  for (int t = 0; t < 2; ++t) {
    int row = wv * 16 + ln;
    pa[t] = *(const short8*)&P[row * 32 + (((4 * t + qd) ^ (row & 7)) << 2)];
  }
#pragma unroll
  for (int nt = 0; nt < 4; ++nt) {
    int n = nt * 16 + ln;
    floatx4 hr = {0.f, 0.f, 0.f, 0.f}, hi = {0.f, 0.f, 0.f, 0.f};
#pragma unroll
    for (int t = 0; t < 2; ++t) {
      short8 b5 = *(const short8*)(rB + (0 * 64 + n) * 64 + t * 32 + qd * 8);
      short8 b6 = *(const short8*)(rB + (1 * 64 + n) * 64 + t * 32 + qd * 8);
      hr = __builtin_amdgcn_mfma_f32_16x16x32_bf16(pa[t], b5, hr, 0, 0, 0);
      hi = __builtin_amdgcn_mfma_f32_16x16x32_bf16(pa[t], b6, hi, 0, 0, 0);
    }
    unsigned* ho = hsp + (size_t)blc * 4096;
#pragma unroll
    for (int j = 0; j < 4; ++j) {
      int s = wv * 16 + qd * 4 + j;
      ho[s * 64 + n] = pack_bf16(hr[j], hi[j]);
    }
  }
}

// ------------------------------------------------------------ MFMA 3x3 conv
// 4-row slabs: LDS 6x66x32 u32 = 50,688 B -> 3 blocks/CU (12 waves).
// cell (yi,xi) = 32 u32 (ci-ordered, groups of 4 xor-swizzled by xi&7).
__global__ __launch_bounds__(256, 3) void k_conv(
    const unsigned* __restrict__ hsp, const short* __restrict__ Wtb,
    float* __restrict__ convout, float2* __restrict__ stats) {
  __shared__ unsigned lds_in[6 * 66 * 32];   // 50,688 B
  const int bl = blockIdx.x >> 4;
  const int slab = blockIdx.x & 15;
  const int y0 = slab * 4;
  const int tid = threadIdx.x;
  // zero x-border cells (xi = 0 and 65 map to padding, always zero)
  for (int i = tid; i < 384; i += 256) {
    int ci = i & 31, j = i >> 5;           // j 0..11
    int yi = j >> 1, xi = (j & 1) ? 65 : 0;
    int slot = (ci >> 2) ^ (xi & 7);
    lds_in[(yi * 66 + xi) * 32 + slot * 4 + (ci & 3)] = 0u;
  }
  // interior staging: 32ci x 6yi x 16 uint4 = 3072 uint4, ci-major lanes
#pragma unroll
  for (int t = 0; t < 12; ++t) {
    int i = t * 256 + tid;
    int ci = i & 31;
    int j = i >> 5;                        // 0..95
    int yi = j >> 4, x4 = j & 15;
    int y = y0 + yi - 1;
    uint4 v = make_uint4(0u, 0u, 0u, 0u);
    if ((unsigned)y < 64u)
      v = *(const uint4*)(hsp + (((size_t)bl * 32 + ci) * 64 + y) * 64 + x4 * 4);
    int xb = 1 + x4 * 4;
#pragma unroll
    for (int jj = 0; jj < 4; ++jj) {
      int xi = xb + jj;
      int slot = (ci >> 2) ^ (xi & 7);
      lds_in[(yi * 66 + xi) * 32 + slot * 4 + (ci & 3)] =
          ((const unsigned*)&v)[jj];
    }
  }
  const int lane = tid & 63;
  const int wv = tid >> 6;
  const int co_t = wv >> 1;
  const int co = co_t * 16 + (lane & 15);
  const int qd = lane >> 4;
  short8 bfrag[18];
  {
    const short* wp = Wtb + (co * 9) * 64 + qd * 8;
#pragma unroll
    for (int tap = 0; tap < 9; ++tap)
#pragma unroll
      for (int kk = 0; kk < 2; ++kk)
        bfrag[tap * 2 + kk] = *(const short8*)(wp + tap * 64 + kk * 32);
  }
  __syncthreads();
  float ssum = 0.f, ssum2 = 0.f;
  const int xl = lane & 15;
  for (int m8 = 0; m8 < 8; ++m8) {
    int mt = (wv & 1) * 8 + m8;
    int ry = mt >> 2;                      // row within 4-row slab
    int x0 = (mt & 3) * 16;
    floatx4 acc = {0.f, 0.f, 0.f, 0.f};
#pragma unroll
    for (int tap = 0; tap < 9; ++tap) {
      int dy = tap / 3, dx = tap - dy * 3;
      int yi = ry + dy;
      int xi = x0 + xl + dx;
#pragma unroll
      for (int kk = 0; kk < 2; ++kk) {
        int slot = ((kk << 2) | qd) ^ (xi & 7);
        const short8 a =
            *(const short8*)&lds_in[(yi * 66 + xi) * 32 + slot * 4];
        acc = __builtin_amdgcn_mfma_f32_16x16x32_bf16(a, bfrag[tap * 2 + kk],
                                                      acc, 0, 0, 0);
      }
    }
    size_t go = (((size_t)bl * 32 + co) * 64 + (y0 + ry)) * 64 + x0 + qd * 4;
    *(float4*)(convout + go) = make_float4(acc[0], acc[1], acc[2], acc[3]);
    ssum  += acc[0] + acc[1] + acc[2] + acc[3];
    ssum2 += acc[0] * acc[0] + acc[1] * acc[1] + acc[2] * acc[2] + acc[3] * acc[3];
  }
  ssum  += __shfl_down(ssum, 32, 64);
  ssum2 += __shfl_down(ssum2, 32, 64);
  ssum  += __shfl_down(ssum, 16, 64);
  ssum2 += __shfl_down(ssum2, 16, 64);
  if (lane < 16)
    stats[((size_t)bl * 32 + co_t * 16 + lane) * 32 + slab * 2 + (wv & 1)] =
        make_float2(ssum, ssum2);
}

// -------------------------------------------------------- LN + residual out
__global__ __launch_bounds__(256) void k_ln(
    const float* __restrict__ convout, const float2* __restrict__ stats,
    const float* __restrict__ x, const float* __restrict__ ln_w,
    const float* __restrict__ ln_b, float* __restrict__ out) {
  const int blc = blockIdx.x;
  const int tid = threadIdx.x;
  __shared__ float sh_mu, sh_rs;
  if (tid < 64) {
    float2 v = (tid < 32) ? stats[(size_t)blc * 32 + tid] : make_float2(0.f, 0.f);
    float s = v.x, s2 = v.y;
#pragma unroll
    for (int o = 16; o > 0; o >>= 1) {
      s += __shfl_down(s, o, 64);
      s2 += __shfl_down(s2, o, 64);
    }
    if (tid == 0) {
      float mu = s * (1.f / 4096.f);
      float var = s2 * (1.f / 4096.f) - mu * mu;
      sh_mu = mu;
      sh_rs = rsqrtf(var + 1e-5f);
    }
  }
  __syncthreads();
  float mu = sh_mu, rs = sh_rs;
  const float4* cp = (const float4*)(convout + (size_t)blc * 4096);
  const float4* xp = (const float4*)(x + (size_t)blc * 4096);
  const float4* lwp = (const float4*)ln_w;
  const float4* lbp = (const float4*)ln_b;
  float4* op = (float4*)(out + (size_t)blc * 4096);
#pragma unroll
  for (int k = 0; k < 4; ++k) {
    int i = tid + k * 256;
    float4 cv = cp[i], xv = xp[i], lw = lwp[i], lb = lbp[i];
    float4 o;
    o.x = xv.x + (cv.x - mu) * rs * lw.x + lb.x;
    o.y = xv.y + (cv.y - mu) * rs * lw.y + lb.y;
    o.z = xv.z + (cv.z - mu) * rs * lw.z + lb.z;
    o.w = xv.w + (cv.w - mu) * rs * lw.w + lb.w;
    op[i] = o;
  }
}

// ------------------------------------------------------------------- launch
extern "C" void kernel_launch(void* const* d_in, const int* in_sizes, int n_in,
                              void* d_out, int out_size, void* d_ws,
                              size_t ws_size, hipStream_t stream) {
  const float* x       = (const float*)d_in[0];
  const float* listT   = (const float*)d_in[1];
  const float* plb     = (const float*)d_in[2];
  const float* dmod    = (const float*)d_in[3];
  const float* fm_W1   = (const float*)d_in[4];
  const float* fm_b1   = (const float*)d_in[5];
  const float* fm_W2   = (const float*)d_in[6];
  const float* fm_b2   = (const float*)d_in[7];
  const float* fscale  = (const float*)d_in[8];
  const float* U_re    = (const float*)d_in[9];
  const float* U_im    = (const float*)d_in[10];
  const float* V_re    = (const float*)d_in[11];
  const float* V_im    = (const float*)d_in[12];
  const float* pW_re   = (const float*)d_in[13];
  const float* pW_im   = (const float*)d_in[14];
  // d_in[15..16] pb_re/pb_im: cropped out, no effect
  const float* convr_w = (const float*)d_in[17];
  // convr_b/convi_b/projc_b (18,20,22): constant over [S,W] -> cancel in LN
  const float* convi_w = (const float*)d_in[19];
  const float* projc_w = (const float*)d_in[21];
  const float* ln_w    = (const float*)d_in[23];
  const float* ln_b    = (const float*)d_in[24];
  float* out = (float*)d_out;

  float* wsf = (float*)d_ws;
  // R0a [0, 8388608): hs (u32 packed bf16) -> later hsp (alias)
  unsigned* hs  = (unsigned*)wsf;
  unsigned* hsp = (unsigned*)wsf;
  // R0b [8388608, 16777216): coefficient mats (2 MB, dead before conv) then convout
  float*    convout = wsf + 8388608;
  unsigned* zqAp  = (unsigned*)(wsf + 8388608);           // 262144 u32
  unsigned* recAp = (unsigned*)(wsf + 8388608 + 262144);  // 131072 u32
  unsigned* recBp = (unsigned*)(wsf + 8388608 + 393216);  // 131072 u32
  float2*   zq  = (float2*)(wsf + 16777216);              // 4,194,304 fl
  size_t off = 16777216 + 4194304;
  float2* zs = (float2*)(wsf + off);
  size_t need_with_zs = (size_t)(off + 4194304 + 470016) * 4;
  bool sep = ws_size >= need_with_zs;
  if (sep) off += 4194304; else zs = zq;
  float2*   lam  = (float2*)(wsf + off);                  // 131,072 fl
  float2*   stats = lam;                                  // alias: lam dead after scan
  float*    gam  = wsf + off + 131072;                    // 65,536 fl
  float*    ctx  = wsf + off + 458752;                    // 2,048 fl
  unsigned* Wtb  = (unsigned*)(wsf + off + 460800);       // 9,216 u32

  k_prep<<<4132, 256, 0, stream>>>(U_re, U_im, V_re, V_im, projc_w,
                                   convr_w, convi_w, x, zqAp, recAp, recBp,
                                   Wtb, ctx);
  k_mix_mlp<<<1088, 256, 0, stream>>>(x, pW_re, pW_im, hs, ctx, listT, plb,
                                      dmod, fm_W1, fm_b1, fm_W2, fm_b2,
                                      fscale, lam, gam);
  k_zq<<<2048, 256, 0, stream>>>(hs, (const short*)zqAp, zq);
  k_scan<<<256, 256, 0, stream>>>(lam, gam, zq, zs);
  k_rec<<<2048, 256, 0, stream>>>(zs, (const short*)recAp, (const short*)recBp, hsp);
  k_conv<<<1024, 256, 0, stream>>>(hsp, (const short*)Wtb, convout, stats);
  k_ln<<<2048, 256, 0, stream>>>(convout, stats, x, ln_w, ln_b, out);
}

// Round 5
// 258.844 us; speedup vs baseline: 1.7851x; 1.0701x over previous
//
#include <hip/hip_runtime.h>

// Dims: B=2, L=32, C=32, S=64, W=64, R=32, MH=32. BL=64, SW=4096.
//
// Reduced pipeline (all GEMM-shaped stages on MFMA bf16):
//  hs  = x ×_c (pW_re + i pW_im)            (MFMA; packed bf16 u32 per complex)
//  coefficient mats zqA/recA/recB = packed DFTs of U/V (computed in k_prep)
//  T2[s][q] = sum_w hs[s][w]·Bq[w][q]       (MFMA, K=2w+p interleaved complex)
//  zq[r][q] = sum_s conj(Uh[s][r])·T2[s][q] (MFMA)
//  scan over l (lam, gamma)                 (fp32, coalesced per-(b,c) blocks)
//  P[s][q]  = sum_r Uh[s][r]·z[r][q]        (MFMA)
//  hsp[s][w]= sum_q P[s][q]·conj(Bq[w][q])  (MFMA, packed bf16 out)
//  out = x + LN(MFMA-conv3x3(hsp; Wtb))     (conv out in bf16, stats in fp32)

typedef __attribute__((ext_vector_type(8))) short short8;
typedef __attribute__((ext_vector_type(4))) float floatx4;

__device__ __forceinline__ unsigned pack_bf16(float re, float im) {
  unsigned a = __float_as_uint(re), b = __float_as_uint(im);
  a = (a + 0x7FFFu + ((a >> 16) & 1u)) >> 16;
  b = (b + 0x7FFFu + ((b >> 16) & 1u)) >> 16;
  return a | (b << 16);
}
__device__ __forceinline__ unsigned short bf16r(float v) {
  unsigned a = __float_as_uint(v);
  return (unsigned short)((a + 0x7FFFu + ((a >> 16) & 1u)) >> 16);
}

// ---------------------- prep: coefficient mats (direct DFT) + weff + ctx
__global__ __launch_bounds__(256) void k_prep(
    const float* __restrict__ U_re, const float* __restrict__ U_im,
    const float* __restrict__ V_re, const float* __restrict__ V_im,
    const float* __restrict__ projc_w,
    const float* __restrict__ convr_w, const float* __restrict__ convi_w,
    const float* __restrict__ x,
    unsigned* __restrict__ zqA, unsigned* __restrict__ recA,
    unsigned* __restrict__ recB, unsigned* __restrict__ Wtb,
    float* __restrict__ ctx) {
  const int bid = blockIdx.x;
  const int tid = threadIdx.x;
  if (bid < 2048) {
    __shared__ float2 tw[64];
    if (tid < 64) {
      float sa, ca;
      sincosf((float)tid * 0.09817477042468103f, &sa, &ca);
      tw[tid] = make_float2(ca, sa);
    }
    __syncthreads();
    int gid = bid * 256 + tid;
    const float *Ar, *Ai;
    int knum, mode, variant;
    bool plus;
    unsigned* dst;
    int didx;
    if (gid < 262144) {                    // zqA
      int c = gid >> 13, mat = (gid >> 11) & 3, m = (gid >> 6) & 31,
          kw = gid & 63;
      knum = kw; mode = m;
      if (mat < 2) { Ar = V_re + c * 2048; Ai = V_im + c * 2048; plus = false; }
      else         { Ar = U_re + c * 2048; Ai = U_im + c * 2048; plus = true; }
      variant = mat; dst = zqA; didx = gid;
    } else {                               // recA / recB
      int rid = gid - 262144;
      int c = rid >> 13, sub = rid & 8191;
      int which = sub >> 11, mm = (sub >> 5) & 63, k2 = sub & 31;
      knum = mm; mode = k2;
      if (which < 2) {
        Ar = U_re + c * 2048; Ai = U_im + c * 2048; plus = true;
        variant = 4 + which; dst = recA;
        didx = ((c * 2 + which) * 64 + mm) * 32 + k2;
      } else {
        Ar = V_re + c * 2048; Ai = V_im + c * 2048; plus = false;
        variant = 4 + which; dst = recB;
        didx = ((c * 2 + which - 2) * 64 + mm) * 32 + k2;
      }
    }
    float sr = 0.f, si = 0.f;
    for (int n = 0; n < 64; ++n) {
      float2 w = tw[(knum * n) & 63];
      float ar = Ar[n * 32 + mode], ai = Ai[n * 32 + mode];
      if (plus) { sr += ar * w.x - ai * w.y; si += ar * w.y + ai * w.x; }
      else      { sr += ar * w.x + ai * w.y; si += ai * w.x - ar * w.y; }
    }
    sr *= 0.125f; si *= 0.125f;
    unsigned pv;
    switch (variant) {
      case 0: pv = pack_bf16(sr, -si); break;   // A1 = (bx, -by)
      case 1: pv = pack_bf16(si, sr); break;    // A2 = (by, bx)
      case 2: pv = pack_bf16(sr, si); break;    // A3 = (ux, uy)
      case 3: pv = pack_bf16(-si, sr); break;   // A4 = (-uy, ux)
      case 4: pv = pack_bf16(sr, -si); break;   // A5 = (ux, -uy)
      case 5: pv = pack_bf16(si, sr); break;    // A6 = (uy, ux)
      case 6: pv = pack_bf16(sr, si); break;    // B5 = (bx, by)
      default: pv = pack_bf16(-si, sr); break;  // B6 = (-by, bx)
    }
    dst[didx] = pv;
  } else if (bid < 2084) {                 // effective conv weights
    int gid = (bid - 2048) * 256 + tid;    // (co*9+tap)*32 + ci
    if (gid < 9216) {
      int co = gid / 288;
      int r2 = gid - co * 288;
      int tap = r2 >> 5, ci = r2 & 31;
      float sr = 0.f, si = 0.f;
      for (int m = 0; m < 32; ++m) {
        sr += projc_w[co * 64 + m]      * convr_w[(m * 32 + ci) * 9 + tap];
        si += projc_w[co * 64 + 32 + m] * convi_w[(m * 32 + ci) * 9 + tap];
      }
      Wtb[gid] = pack_bf16(sr, si);
    }
  } else {                                 // ctx = mean over S,W
    int blc = bid - 2084;
    const float* p = x + (size_t)blc * 4096;
    float s = 0.f;
    for (int i = tid; i < 4096; i += 256) s += p[i];
    for (int o = 32; o > 0; o >>= 1) s += __shfl_down(s, o, 64);
    __shared__ float wsum[4];
    if ((tid & 63) == 0) wsum[tid >> 6] = s;
    __syncthreads();
    if (tid == 0)
      ctx[blc] = (wsum[0] + wsum[1] + wsum[2] + wsum[3]) * (1.f / 4096.f);
  }
}

// ----------------------------------------------- MFMA mix (+ mlp piggyback)
// Blocks 0..511: (bl, 512-px segment). hs[d][px] = sum_ci pW[ci][d]·x[ci][px].
// LDS B-layout: [px][16 u32] (ci-pairs), row stride 20 u32, chunk swizzle.
__global__ __launch_bounds__(256) void k_mix_mlp(
    const float* __restrict__ x, const float* __restrict__ pWr,
    const float* __restrict__ pWi, unsigned* __restrict__ hs,
    const float* __restrict__ ctx, const float* __restrict__ listT,
    const float* __restrict__ plb, const float* __restrict__ dmod,
    const float* __restrict__ W1, const float* __restrict__ b1,
    const float* __restrict__ W2, const float* __restrict__ b2,
    const float* __restrict__ fscale,
    float2* __restrict__ lam, float* __restrict__ gam) {
  __shared__ unsigned xb_s[512 * 20];   // 40 KB
  __shared__ float mid_s[32];
  const int tid = threadIdx.x;
  if (blockIdx.x < 512) {
    const int bl = blockIdx.x >> 3;
    const int pxbase = (blockIdx.x & 7) * 512;
    const float* xb = x + (size_t)bl * 131072 + pxbase;
    // stage x -> LDS bf16 [px][ci], packed ci-pairs
#pragma unroll
    for (int t = 0; t < 8; ++t) {
      int i = t * 256 + tid;
      int c2 = i & 15, g4 = i >> 4;     // ci-pair, float4-group (0..127)
      float4 a = *(const float4*)(xb + (2 * c2) * 4096 + g4 * 4);
      float4 b = *(const float4*)(xb + (2 * c2 + 1) * 4096 + g4 * 4);
#pragma unroll
      for (int j = 0; j < 4; ++j) {
        int px = g4 * 4 + j;
        xb_s[px * 20 + (((c2 >> 2) ^ (px & 3)) << 2) + (c2 & 3)] =
            pack_bf16(((const float*)&a)[j], ((const float*)&b)[j]);
      }
    }
    const int lane = tid & 63, wv = tid >> 6;
    const int qd = lane >> 4, ln = lane & 15;
    // A-fragments from pW (bf16): A[m=d][k=ci]
    short8 arL, aiL, arH, aiH;
#pragma unroll
    for (int j = 0; j < 8; ++j) {
      int ci = qd * 8 + j;
      ((short*)&arL)[j] = (short)bf16r(pWr[ci * 32 + ln]);
      ((short*)&aiL)[j] = (short)bf16r(pWi[ci * 32 + ln]);
      ((short*)&arH)[j] = (short)bf16r(pWr[ci * 32 + 16 + ln]);
      ((short*)&aiH)[j] = (short)bf16r(pWi[ci * 32 + 16 + ln]);
    }
    __syncthreads();
#pragma unroll
    for (int pt = 0; pt < 8; ++pt) {
      int pxt = wv * 8 + pt;
      int pxl = pxt * 16 + ln;
      short8 bfr =
          *(const short8*)&xb_s[pxl * 20 + ((qd ^ (pxl & 3)) << 2)];
      floatx4 dRL = {0.f, 0.f, 0.f, 0.f}, dIL = {0.f, 0.f, 0.f, 0.f};
      floatx4 dRH = {0.f, 0.f, 0.f, 0.f}, dIH = {0.f, 0.f, 0.f, 0.f};
      dRL = __builtin_amdgcn_mfma_f32_16x16x32_bf16(arL, bfr, dRL, 0, 0, 0);
      dIL = __builtin_amdgcn_mfma_f32_16x16x32_bf16(aiL, bfr, dIL, 0, 0, 0);
      dRH = __builtin_amdgcn_mfma_f32_16x16x32_bf16(arH, bfr, dRH, 0, 0, 0);
      dIH = __builtin_amdgcn_mfma_f32_16x16x32_bf16(aiH, bfr, dIH, 0, 0, 0);
      unsigned* ho = hs + (size_t)bl * 131072 + pxbase + pxt * 16 + ln;
#pragma unroll
      for (int j = 0; j < 4; ++j) {
        ho[(qd * 4 + j) * 4096] = pack_bf16(dRL[j], dIL[j]);
        ho[(16 + qd * 4 + j) * 4096] = pack_bf16(dRH[j], dIH[j]);
      }
    }
  } else {
    int bl = blockIdx.x - 512;
    float dt = listT[bl];
    if (tid < 32) {
      float a = b1[tid];
      for (int j = 0; j < 32; ++j) a += ctx[bl * 32 + j] * W1[j * 32 + tid];
      a += dt * W1[1024 + tid];
      mid_s[tid] = tanhf(a);
    }
    __syncthreads();
    float fs = fscale[0];
#pragma unroll
    for (int u = 0; u < 4; ++u) {
      int cr = u * 256 + tid;
      int col = cr * 2;
      float m0 = b2[col], m1 = b2[col + 1];
      for (int h = 0; h < 32; ++h) {
        float mh = mid_s[h];
        float2 w2 = *(const float2*)&W2[h * 2048 + col];
        m0 += mh * w2.x;
        m1 += mh * w2.y;
      }
      float dnu = fs * tanhf(m0);
      float dth = fs * tanhf(m1);
      float nub = expf(plb[cr] + dmod[cr]);
      float thb = expf(plb[1024 + cr] + dmod[1024 + cr]);
      float nut = fmaxf(nub * dt + dnu, 1e-6f);
      float tht = thb * dt + dth;
      float e = expf(-nut);
      float sa, ca;
      sincosf(tht, &sa, &ca);
      float g = sqrtf(fmaxf(1.f - expf(-2.f * nut), 1e-12f));
      int o = bl * 1024 + cr;
      lam[o] = make_float2(e * ca, e * sa);
      gam[o] = g;
    }
  }
}

// ------------------------------------------------------------ MFMA zq
__global__ __launch_bounds__(256) void k_zq(const unsigned* __restrict__ hs,
                                            const short* __restrict__ zqA,
                                            float2* __restrict__ zq) {
  __shared__ unsigned HsB[4096];   // [s][w-chunks xor-swizzled], 16 KB
  __shared__ unsigned T2[2048];    // [q][s-chunks xor-swizzled], 8 KB
  const int blc = blockIdx.x;
  const int c = blc & 31;
  const int tid = threadIdx.x;
  const int lane = tid & 63, wv = tid >> 6;
  const int qd = lane >> 4, ln = lane & 15;
  const int mt = wv >> 1, nth = wv & 1;
  {
    const uint4* hp = (const uint4*)(hs + (size_t)blc * 4096);
#pragma unroll
    for (int it = 0; it < 4; ++it) {
      int i4 = tid + it * 256;
      uint4 v = hp[i4];
      int s = i4 >> 4, w4 = i4 & 15;
      *(uint4*)&HsB[s * 64 + ((w4 ^ (s & 15)) << 2)] = v;
    }
  }
  const short* zA = zqA + (size_t)c * 4 * 32 * 128;
  short8 a1[4], a2[4], a3[4], a4[4];
#pragma unroll
  for (int t = 0; t < 4; ++t) {
    int row = mt * 16 + ln;
    a1[t] = *(const short8*)(zA + (0 * 32 + row) * 128 + t * 32 + qd * 8);
    a2[t] = *(const short8*)(zA + (1 * 32 + row) * 128 + t * 32 + qd * 8);
    a3[t] = *(const short8*)(zA + (2 * 32 + row) * 128 + t * 32 + qd * 8);
    a4[t] = *(const short8*)(zA + (3 * 32 + row) * 128 + t * 32 + qd * 8);
  }
  __syncthreads();
#pragma unroll
  for (int nti = 0; nti < 2; ++nti) {
    int nt = nth * 2 + nti;
    int n = nt * 16 + ln;
    floatx4 accr = {0.f, 0.f, 0.f, 0.f}, acci = {0.f, 0.f, 0.f, 0.f};
#pragma unroll
    for (int t = 0; t < 4; ++t) {
      short8 b = *(const short8*)&HsB[n * 64 + (((4 * t + qd) ^ (n & 15)) << 2)];
      accr = __builtin_amdgcn_mfma_f32_16x16x32_bf16(a1[t], b, accr, 0, 0, 0);
      acci = __builtin_amdgcn_mfma_f32_16x16x32_bf16(a2[t], b, acci, 0, 0, 0);
    }
#pragma unroll
    for (int j = 0; j < 4; ++j) {
      int q = mt * 16 + qd * 4 + j;
      int s = n;
      T2[q * 64 + (((s >> 2) ^ (q & 15)) << 2) + (s & 3)] = pack_bf16(accr[j], acci[j]);
    }
  }
  __syncthreads();
  {
    const int mt2 = wv >> 1, nt2 = wv & 1;
    int n = nt2 * 16 + ln;
    floatx4 zr = {0.f, 0.f, 0.f, 0.f}, zi = {0.f, 0.f, 0.f, 0.f};
#pragma unroll
    for (int t = 0; t < 4; ++t) {
      short8 b = *(const short8*)&T2[n * 64 + (((4 * t + qd) ^ (n & 15)) << 2)];
      zr = __builtin_amdgcn_mfma_f32_16x16x32_bf16(a3[t], b, zr, 0, 0, 0);
      zi = __builtin_amdgcn_mfma_f32_16x16x32_bf16(a4[t], b, zi, 0, 0, 0);
    }
    float2* zo = zq + (size_t)blc * 1024;
#pragma unroll
    for (int j = 0; j < 4; ++j) {
      int r = mt2 * 16 + qd * 4 + j;
      zo[r * 32 + n] = make_float2(zr[j], zi[j]);
    }
  }
}

// ------------------------------------------- linear scan, coalesced per (b,c)
__global__ __launch_bounds__(256) void k_scan(const float2* __restrict__ lam,
                                              const float* __restrict__ gam,
                                              const float2* zin,
                                              float2* zout) {
  const int b = blockIdx.x >> 5, c = blockIdx.x & 31;
  const int tid = threadIdx.x;
  float2 st[4] = {{0.f, 0.f}, {0.f, 0.f}, {0.f, 0.f}, {0.f, 0.f}};
  float2 v[4], lmv[4];
  float gv[4];
  {
    size_t zb = ((size_t)(b * 32) * 32 + c) * 1024;
    int pb = (b * 32) * 1024 + c * 32;
#pragma unroll
    for (int j = 0; j < 4; ++j) {
      int rq = tid + 256 * j;
      v[j] = zin[zb + rq];
      lmv[j] = lam[pb + (rq >> 5)];
      gv[j] = gam[pb + (rq >> 5)];
    }
  }
  for (int t = 0; t < 32; ++t) {
    float2 nv[4], nlm[4];
    float ng[4];
    if (t < 31) {
      size_t zb = ((size_t)(b * 32 + t + 1) * 32 + c) * 1024;
      int pb = (b * 32 + t + 1) * 1024 + c * 32;
#pragma unroll
      for (int j = 0; j < 4; ++j) {
        int rq = tid + 256 * j;
        nv[j] = zin[zb + rq];
        nlm[j] = lam[pb + (rq >> 5)];
        ng[j] = gam[pb + (rq >> 5)];
      }
    }
    size_t zb = ((size_t)(b * 32 + t) * 32 + c) * 1024;
#pragma unroll
    for (int j = 0; j < 4; ++j) {
      float nr = lmv[j].x * st[j].x - lmv[j].y * st[j].y + gv[j] * v[j].x;
      float ni = lmv[j].x * st[j].y + lmv[j].y * st[j].x + gv[j] * v[j].y;
      st[j] = make_float2(nr, ni);
      zout[zb + tid + 256 * j] = st[j];
    }
#pragma unroll
    for (int j = 0; j < 4; ++j) { v[j] = nv[j]; lmv[j] = nlm[j]; gv[j] = ng[j]; }
  }
}

// ------------------------------------------------------------ MFMA rec
__global__ __launch_bounds__(256) void k_rec(const float2* __restrict__ zs,
                                             const short* __restrict__ recA,
                                             const short* __restrict__ recB,
                                             unsigned* __restrict__ hsp) {
  __shared__ unsigned zB[1024];
  __shared__ unsigned P[2048];
  const int blc = blockIdx.x;
  const int c = blc & 31;
  const int tid = threadIdx.x;
  const int lane = tid & 63, wv = tid >> 6;
  const int qd = lane >> 4, ln = lane & 15;
  {
    const float2* zp = zs + (size_t)blc * 1024;
#pragma unroll
    for (int it = 0; it < 4; ++it) {
      int i = tid + it * 256;
      float2 v = zp[i];
      int r = i >> 5, q = i & 31;
      zB[q * 32 + (((r >> 2) ^ (q & 7)) << 2) + (r & 3)] = pack_bf16(v.x, v.y);
    }
  }
  const short* rA = recA + (size_t)c * 2 * 64 * 64;
  short8 a5[2], a6[2];
#pragma unroll
  for (int t = 0; t < 2; ++t) {
    int row = wv * 16 + ln;
    a5[t] = *(const short8*)(rA + (0 * 64 + row) * 64 + t * 32 + qd * 8);
    a6[t] = *(const short8*)(rA + (1 * 64 + row) * 64 + t * 32 + qd * 8);
  }
  __syncthreads();
#pragma unroll
  for (int nt = 0; nt < 2; ++nt) {
    int n = nt * 16 + ln;
    floatx4 pr = {0.f, 0.f, 0.f, 0.f}, pi = {0.f, 0.f, 0.f, 0.f};
#pragma unroll
    for (int t = 0; t < 2; ++t) {
      short8 b = *(const short8*)&zB[n * 32 + (((4 * t + qd) ^ (n & 7)) << 2)];
      pr = __builtin_amdgcn_mfma_f32_16x16x32_bf16(a5[t], b, pr, 0, 0, 0);
      pi = __builtin_amdgcn_mfma_f32_16x16x32_bf16(a6[t], b, pi, 0, 0, 0);
    }
#pragma unroll
    for (int j = 0; j < 4; ++j) {
      int s = wv * 16 + qd * 4 + j;
      int q = n;
      P[s * 32 + (((q >> 2) ^ (s & 7)) << 2) + (q & 3)] = pack_bf16(pr[j], pi[j]);
    }
  }
  __syncthreads();
  const short* rB = recB + (size_t)c * 2 * 64 * 64;
  short8 pa[2];
#pragma unroll
  for (int t = 0; t < 2; ++t) {
    int row = wv * 16 + ln;
    pa[t] = *(const short8*)&P[row * 32 + (((4 * t + qd) ^ (row & 7)) << 2)];
  }
#pragma unroll
  for (int nt = 0; nt < 4; ++nt) {
    int n = nt * 16 + ln;
    floatx4 hr = {0.f, 0.f, 0.f, 0.f}, hi = {0.f, 0.f, 0.f, 0.f};
#pragma unroll
    for (int t = 0; t < 2; ++t) {
      short8 b5 = *(const short8*)(rB + (0 * 64 + n) * 64 + t * 32 + qd * 8);
      short8 b6 = *(const short8*)(rB + (1 * 64 + n) * 64 + t * 32 + qd * 8);
      hr = __builtin_amdgcn_mfma_f32_16x16x32_bf16(pa[t], b5, hr, 0, 0, 0);
      hi = __builtin_amdgcn_mfma_f32_16x16x32_bf16(pa[t], b6, hi, 0, 0, 0);
    }
    unsigned* ho = hsp + (size_t)blc * 4096;
#pragma unroll
    for (int j = 0; j < 4; ++j) {
      int s = wv * 16 + qd * 4 + j;
      ho[s * 64 + n] = pack_bf16(hr[j], hi[j]);
    }
  }
}

// ------------------------------------------------------------ MFMA 3x3 conv
// 4-row slabs; each wave owns one x-quarter and BOTH co-groups (2 MFMAs per
// A-read -> ds_read halved). Output bf16.
__global__ __launch_bounds__(256, 2) void k_conv(
    const unsigned* __restrict__ hsp, const short* __restrict__ Wtb,
    unsigned short* __restrict__ convout, float2* __restrict__ stats) {
  __shared__ unsigned lds_in[6 * 66 * 32];   // 50,688 B
  const int bl = blockIdx.x >> 4;
  const int slab = blockIdx.x & 15;
  const int y0 = slab * 4;
  const int tid = threadIdx.x;
  for (int i = tid; i < 384; i += 256) {     // zero x-border cells
    int ci = i & 31, j = i >> 5;
    int yi = j >> 1, xi = (j & 1) ? 65 : 0;
    int slot = (ci >> 2) ^ (xi & 7);
    lds_in[(yi * 66 + xi) * 32 + slot * 4 + (ci & 3)] = 0u;
  }
#pragma unroll
  for (int t = 0; t < 12; ++t) {             // interior staging
    int i = t * 256 + tid;
    int ci = i & 31;
    int j = i >> 5;
    int yi = j >> 4, x4 = j & 15;
    int y = y0 + yi - 1;
    uint4 v = make_uint4(0u, 0u, 0u, 0u);
    if ((unsigned)y < 64u)
      v = *(const uint4*)(hsp + (((size_t)bl * 32 + ci) * 64 + y) * 64 + x4 * 4);
    int xb = 1 + x4 * 4;
#pragma unroll
    for (int jj = 0; jj < 4; ++jj) {
      int xi = xb + jj;
      int slot = (ci >> 2) ^ (xi & 7);
      lds_in[(yi * 66 + xi) * 32 + slot * 4 + (ci & 3)] =
          ((const unsigned*)&v)[jj];
    }
  }
  const int lane = tid & 63;
  const int wv = tid >> 6;
  const int co = lane & 15;
  const int qd = lane >> 4;
  short8 bL[18], bH[18];
  {
    const short* wpL = Wtb + (co * 9) * 64 + qd * 8;
    const short* wpH = Wtb + ((co + 16) * 9) * 64 + qd * 8;
#pragma unroll
    for (int tap = 0; tap < 9; ++tap)
#pragma unroll
      for (int kk = 0; kk < 2; ++kk) {
        bL[tap * 2 + kk] = *(const short8*)(wpL + tap * 64 + kk * 32);
        bH[tap * 2 + kk] = *(const short8*)(wpH + tap * 64 + kk * 32);
      }
  }
  __syncthreads();
  float sL = 0.f, s2L = 0.f, sH = 0.f, s2H = 0.f;
  const int x0 = wv * 16;
  const int xl = lane & 15;
  for (int ry = 0; ry < 4; ++ry) {
    floatx4 aL = {0.f, 0.f, 0.f, 0.f}, aH = {0.f, 0.f, 0.f, 0.f};
#pragma unroll
    for (int tap = 0; tap < 9; ++tap) {
      int dy = tap / 3, dx = tap - dy * 3;
      int yi = ry + dy;
      int xi = x0 + xl + dx;
#pragma unroll
      for (int kk = 0; kk < 2; ++kk) {
        int slot = ((kk << 2) | qd) ^ (xi & 7);
        const short8 a =
            *(const short8*)&lds_in[(yi * 66 + xi) * 32 + slot * 4];
        aL = __builtin_amdgcn_mfma_f32_16x16x32_bf16(a, bL[tap * 2 + kk], aL, 0, 0, 0);
        aH = __builtin_amdgcn_mfma_f32_16x16x32_bf16(a, bH[tap * 2 + kk], aH, 0, 0, 0);
      }
    }
    size_t goL = (((size_t)bl * 32 + co) * 64 + (y0 + ry)) * 64 + x0 + qd * 4;
    size_t goH = goL + (size_t)16 * 4096;
    *(uint2*)(convout + goL) =
        make_uint2(pack_bf16(aL[0], aL[1]), pack_bf16(aL[2], aL[3]));
    *(uint2*)(convout + goH) =
        make_uint2(pack_bf16(aH[0], aH[1]), pack_bf16(aH[2], aH[3]));
#pragma unroll
    for (int j = 0; j < 4; ++j) {
      sL += aL[j]; s2L += aL[j] * aL[j];
      sH += aH[j]; s2H += aH[j] * aH[j];
    }
  }
  sL += __shfl_down(sL, 32, 64);  s2L += __shfl_down(s2L, 32, 64);
  sH += __shfl_down(sH, 32, 64);  s2H += __shfl_down(s2H, 32, 64);
  sL += __shfl_down(sL, 16, 64);  s2L += __shfl_down(s2L, 16, 64);
  sH += __shfl_down(sH, 16, 64);  s2H += __shfl_down(s2H, 16, 64);
  if (lane < 16) {
    stats[((size_t)bl * 32 + lane) * 64 + slab * 4 + wv] = make_float2(sL, s2L);
    stats[((size_t)bl * 32 + 16 + lane) * 64 + slab * 4 + wv] =
        make_float2(sH, s2H);
  }
}

// -------------------------------------------------------- LN + residual out
__global__ __launch_bounds__(256) void k_ln(
    const unsigned short* __restrict__ convout,
    const float2* __restrict__ stats, const float* __restrict__ x,
    const float* __restrict__ ln_w, const float* __restrict__ ln_b,
    float* __restrict__ out) {
  const int blc = blockIdx.x;
  const int tid = threadIdx.x;
  __shared__ float sh_mu, sh_rs;
  if (tid < 64) {
    float2 v = stats[(size_t)blc * 64 + tid];
    float s = v.x, s2 = v.y;
#pragma unroll
    for (int o = 32; o > 0; o >>= 1) {
      s += __shfl_down(s, o, 64);
      s2 += __shfl_down(s2, o, 64);
    }
    if (tid == 0) {
      float mu = s * (1.f / 4096.f);
      float var = s2 * (1.f / 4096.f) - mu * mu;
      sh_mu = mu;
      sh_rs = rsqrtf(var + 1e-5f);
    }
  }
  __syncthreads();
  float mu = sh_mu, rs = sh_rs;
  const uint2* cp = (const uint2*)(convout + (size_t)blc * 4096);
  const float4* xp = (const float4*)(x + (size_t)blc * 4096);
  const float4* lwp = (const float4*)ln_w;
  const float4* lbp = (const float4*)ln_b;
  float4* op = (float4*)(out + (size_t)blc * 4096);
#pragma unroll
  for (int k = 0; k < 4; ++k) {
    int i = tid + k * 256;
    uint2 cv = cp[i];
    float4 xv = xp[i], lw = lwp[i], lb = lbp[i];
    float c0 = __uint_as_float(cv.x << 16);
    float c1 = __uint_as_float(cv.x & 0xFFFF0000u);
    float c2 = __uint_as_float(cv.y << 16);
    float c3 = __uint_as_float(cv.y & 0xFFFF0000u);
    float4 o;
    o.x = xv.x + (c0 - mu) * rs * lw.x + lb.x;
    o.y = xv.y + (c1 - mu) * rs * lw.y + lb.y;
    o.z = xv.z + (c2 - mu) * rs * lw.z + lb.z;
    o.w = xv.w + (c3 - mu) * rs * lw.w + lb.w;
    op[i] = o;
  }
}

// ------------------------------------------------------------------- launch
extern "C" void kernel_launch(void* const* d_in, const int* in_sizes, int n_in,
                              void* d_out, int out_size, void* d_ws,
                              size_t ws_size, hipStream_t stream) {
  const float* x       = (const float*)d_in[0];
  const float* listT   = (const float*)d_in[1];
  const float* plb     = (const float*)d_in[2];
  const float* dmod    = (const float*)d_in[3];
  const float* fm_W1   = (const float*)d_in[4];
  const float* fm_b1   = (const float*)d_in[5];
  const float* fm_W2   = (const float*)d_in[6];
  const float* fm_b2   = (const float*)d_in[7];
  const float* fscale  = (const float*)d_in[8];
  const float* U_re    = (const float*)d_in[9];
  const float* U_im    = (const float*)d_in[10];
  const float* V_re    = (const float*)d_in[11];
  const float* V_im    = (const float*)d_in[12];
  const float* pW_re   = (const float*)d_in[13];
  const float* pW_im   = (const float*)d_in[14];
  // d_in[15..16] pb_re/pb_im: cropped out, no effect
  const float* convr_w = (const float*)d_in[17];
  // convr_b/convi_b/projc_b (18,20,22): constant over [S,W] -> cancel in LN
  const float* convi_w = (const float*)d_in[19];
  const float* projc_w = (const float*)d_in[21];
  const float* ln_w    = (const float*)d_in[23];
  const float* ln_b    = (const float*)d_in[24];
  float* out = (float*)d_out;

  float* wsf = (float*)d_ws;
  // R0a [0, 8388608): hs (u32 packed bf16) -> later hsp (alias)
  unsigned* hs  = (unsigned*)wsf;
  unsigned* hsp = (unsigned*)wsf;
  // R0b [8388608, 16777216): coeff mats (dead before conv), then convout(bf16)+stats
  unsigned* zqAp  = (unsigned*)(wsf + 8388608);           // 262144 u32
  unsigned* recAp = (unsigned*)(wsf + 8388608 + 262144);  // 131072 u32
  unsigned* recBp = (unsigned*)(wsf + 8388608 + 393216);  // 131072 u32
  unsigned short* convout = (unsigned short*)(wsf + 8388608);  // 8388608 u16
  float2*   stats = (float2*)(wsf + 12582912);            // 131072 float2
  float2*   zq  = (float2*)(wsf + 16777216);              // 4,194,304 fl
  size_t off = 16777216 + 4194304;
  float2* zs = (float2*)(wsf + off);
  size_t need_with_zs = (size_t)(off + 4194304 + 470016) * 4;
  bool sep = ws_size >= need_with_zs;
  if (sep) off += 4194304; else zs = zq;
  float2*   lam  = (float2*)(wsf + off);                  // 131,072 fl
  float*    gam  = wsf + off + 131072;                    // 65,536 fl
  float*    ctx  = wsf + off + 458752;                    // 2,048 fl
  unsigned* Wtb  = (unsigned*)(wsf + off + 460800);       // 9,216 u32

  k_prep<<<4132, 256, 0, stream>>>(U_re, U_im, V_re, V_im, projc_w,
                                   convr_w, convi_w, x, zqAp, recAp, recBp,
                                   Wtb, ctx);
  k_mix_mlp<<<576, 256, 0, stream>>>(x, pW_re, pW_im, hs, ctx, listT, plb,
                                     dmod, fm_W1, fm_b1, fm_W2, fm_b2,
                                     fscale, lam, gam);
  k_zq<<<2048, 256, 0, stream>>>(hs, (const short*)zqAp, zq);
  k_scan<<<64, 256, 0, stream>>>(lam, gam, zq, zs);
  k_rec<<<2048, 256, 0, stream>>>(zs, (const short*)recAp, (const short*)recBp, hsp);
  k_conv<<<1024, 256, 0, stream>>>(hsp, (const short*)Wtb, convout, stats);
  k_ln<<<2048, 256, 0, stream>>>(convout, stats, x, ln_w, ln_b, out);
}

// Round 6
// 250.704 us; speedup vs baseline: 1.8431x; 1.0325x over previous
//
#include <hip/hip_runtime.h>

// Dims: B=2, L=32, C=32, S=64, W=64, R=32, MH=32. BL=64, SW=4096.
//
// Reduced pipeline (all GEMM-shaped stages on MFMA bf16):
//  hs  = x ×_c (pW_re + i pW_im)            (MFMA; packed bf16 u32 per complex)
//  coefficient mats zqA/recA/recB = packed DFTs of U/V (computed in k_prep)
//  T2[s][q] = sum_w hs[s][w]·Bq[w][q]       (MFMA, K=2w+p interleaved complex)
//  zq[r][q] = sum_s conj(Uh[s][r])·T2[s][q] (MFMA)
//  scan over l (lam, gamma)                 (fp32, 256-block prefetched)
//  P[s][q]  = sum_r Uh[s][r]·z[r][q]        (MFMA)
//  hsp[s][w]= sum_q P[s][q]·conj(Bq[w][q])  (MFMA, packed bf16 out)
//  out = x + LN(MFMA-conv3x3(hsp; Wtb))     (conv out in bf16, stats in fp32)

typedef __attribute__((ext_vector_type(8))) short short8;
typedef __attribute__((ext_vector_type(4))) float floatx4;

__device__ __forceinline__ unsigned pack_bf16(float re, float im) {
  unsigned a = __float_as_uint(re), b = __float_as_uint(im);
  a = (a + 0x7FFFu + ((a >> 16) & 1u)) >> 16;
  b = (b + 0x7FFFu + ((b >> 16) & 1u)) >> 16;
  return a | (b << 16);
}
__device__ __forceinline__ unsigned short bf16r(float v) {
  unsigned a = __float_as_uint(v);
  return (unsigned short)((a + 0x7FFFu + ((a >> 16) & 1u)) >> 16);
}

// ---------------------- prep: coefficient mats (direct DFT) + weff + ctx-zero
__global__ __launch_bounds__(256) void k_prep(
    const float* __restrict__ U_re, const float* __restrict__ U_im,
    const float* __restrict__ V_re, const float* __restrict__ V_im,
    const float* __restrict__ projc_w,
    const float* __restrict__ convr_w, const float* __restrict__ convi_w,
    unsigned* __restrict__ zqA, unsigned* __restrict__ recA,
    unsigned* __restrict__ recB, unsigned* __restrict__ Wtb,
    float* __restrict__ ctx) {
  const int bid = blockIdx.x;
  const int tid = threadIdx.x;
  if (bid < 2048) {
    __shared__ float2 tw[64];
    if (tid < 64) {
      float sa, ca;
      sincosf((float)tid * 0.09817477042468103f, &sa, &ca);
      tw[tid] = make_float2(ca, sa);
    }
    __syncthreads();
    int gid = bid * 256 + tid;
    const float *Ar, *Ai;
    int knum, mode, variant;
    bool plus;
    unsigned* dst;
    int didx;
    if (gid < 262144) {                    // zqA
      int c = gid >> 13, mat = (gid >> 11) & 3, m = (gid >> 6) & 31,
          kw = gid & 63;
      knum = kw; mode = m;
      if (mat < 2) { Ar = V_re + c * 2048; Ai = V_im + c * 2048; plus = false; }
      else         { Ar = U_re + c * 2048; Ai = U_im + c * 2048; plus = true; }
      variant = mat; dst = zqA; didx = gid;
    } else {                               // recA / recB
      int rid = gid - 262144;
      int c = rid >> 13, sub = rid & 8191;
      int which = sub >> 11, mm = (sub >> 5) & 63, k2 = sub & 31;
      knum = mm; mode = k2;
      if (which < 2) {
        Ar = U_re + c * 2048; Ai = U_im + c * 2048; plus = true;
        variant = 4 + which; dst = recA;
        didx = ((c * 2 + which) * 64 + mm) * 32 + k2;
      } else {
        Ar = V_re + c * 2048; Ai = V_im + c * 2048; plus = false;
        variant = 4 + which; dst = recB;
        didx = ((c * 2 + which - 2) * 64 + mm) * 32 + k2;
      }
    }
    float sr = 0.f, si = 0.f;
    for (int n = 0; n < 64; ++n) {
      float2 w = tw[(knum * n) & 63];
      float ar = Ar[n * 32 + mode], ai = Ai[n * 32 + mode];
      if (plus) { sr += ar * w.x - ai * w.y; si += ar * w.y + ai * w.x; }
      else      { sr += ar * w.x + ai * w.y; si += ai * w.x - ar * w.y; }
    }
    sr *= 0.125f; si *= 0.125f;
    unsigned pv;
    switch (variant) {
      case 0: pv = pack_bf16(sr, -si); break;   // A1 = (bx, -by)
      case 1: pv = pack_bf16(si, sr); break;    // A2 = (by, bx)
      case 2: pv = pack_bf16(sr, si); break;    // A3 = (ux, uy)
      case 3: pv = pack_bf16(-si, sr); break;   // A4 = (-uy, ux)
      case 4: pv = pack_bf16(sr, -si); break;   // A5 = (ux, -uy)
      case 5: pv = pack_bf16(si, sr); break;    // A6 = (uy, ux)
      case 6: pv = pack_bf16(sr, si); break;    // B5 = (bx, by)
      default: pv = pack_bf16(-si, sr); break;  // B6 = (-by, bx)
    }
    dst[didx] = pv;
  } else if (bid < 2084) {                 // effective conv weights
    int gid = (bid - 2048) * 256 + tid;    // (co*9+tap)*32 + ci
    if (gid < 9216) {
      int co = gid / 288;
      int r2 = gid - co * 288;
      int tap = r2 >> 5, ci = r2 & 31;
      float sr = 0.f, si = 0.f;
      for (int m = 0; m < 32; ++m) {
        sr += projc_w[co * 64 + m]      * convr_w[(m * 32 + ci) * 9 + tap];
        si += projc_w[co * 64 + 32 + m] * convi_w[(m * 32 + ci) * 9 + tap];
      }
      Wtb[gid] = pack_bf16(sr, si);
    }
  } else {                                 // zero ctx (accumulated by k_mix)
    for (int i = tid; i < 2048; i += 256) ctx[i] = 0.f;
  }
}

// --------------------------------------- MFMA mix (+ ctx partial accumulate)
// 512 blocks: (bl, 512-px segment). hs[d][px] = sum_ci pW[ci][d]·x[ci][px].
// LDS B-layout: [px][16 u32] (ci-pairs), row stride 20 u32, chunk swizzle.
__global__ __launch_bounds__(256) void k_mix(
    const float* __restrict__ x, const float* __restrict__ pWr,
    const float* __restrict__ pWi, unsigned* __restrict__ hs,
    float* __restrict__ ctx) {
  __shared__ unsigned xb_s[512 * 20];   // 40 KB
  __shared__ float red[16][16][2];      // ctx partials [c2][w][pair]
  const int tid = threadIdx.x;
  const int bl = blockIdx.x >> 3;
  const int pxbase = (blockIdx.x & 7) * 512;
  const float* xb = x + (size_t)bl * 131072 + pxbase;
  float csa = 0.f, csb = 0.f;
#pragma unroll
  for (int t = 0; t < 8; ++t) {
    int i = t * 256 + tid;
    int c2 = i & 15, g4 = i >> 4;       // c2 == tid&15 for all t
    float4 a = *(const float4*)(xb + (2 * c2) * 4096 + g4 * 4);
    float4 b = *(const float4*)(xb + (2 * c2 + 1) * 4096 + g4 * 4);
    csa += a.x + a.y + a.z + a.w;
    csb += b.x + b.y + b.z + b.w;
#pragma unroll
    for (int j = 0; j < 4; ++j) {
      int px = g4 * 4 + j;
      xb_s[px * 20 + (((c2 >> 2) ^ (px & 3)) << 2) + (c2 & 3)] =
          pack_bf16(((const float*)&a)[j], ((const float*)&b)[j]);
    }
  }
  red[tid & 15][tid >> 4][0] = csa;
  red[tid & 15][tid >> 4][1] = csb;
  const int lane = tid & 63, wv = tid >> 6;
  const int qd = lane >> 4, ln = lane & 15;
  short8 arL, aiL, arH, aiH;
#pragma unroll
  for (int j = 0; j < 8; ++j) {
    int ci = qd * 8 + j;
    ((short*)&arL)[j] = (short)bf16r(pWr[ci * 32 + ln]);
    ((short*)&aiL)[j] = (short)bf16r(pWi[ci * 32 + ln]);
    ((short*)&arH)[j] = (short)bf16r(pWr[ci * 32 + 16 + ln]);
    ((short*)&aiH)[j] = (short)bf16r(pWi[ci * 32 + 16 + ln]);
  }
  __syncthreads();
  if (tid < 32) {                       // ctx accumulate (1 atomic per ci)
    int c2 = tid >> 1, part = tid & 1;
    float s = 0.f;
#pragma unroll
    for (int w = 0; w < 16; ++w) s += red[c2][w][part];
    atomicAdd(&ctx[bl * 32 + 2 * c2 + part], s * (1.f / 4096.f));
  }
#pragma unroll
  for (int pt = 0; pt < 8; ++pt) {
    int pxt = wv * 8 + pt;
    int pxl = pxt * 16 + ln;
    short8 bfr = *(const short8*)&xb_s[pxl * 20 + ((qd ^ (pxl & 3)) << 2)];
    floatx4 dRL = {0.f, 0.f, 0.f, 0.f}, dIL = {0.f, 0.f, 0.f, 0.f};
    floatx4 dRH = {0.f, 0.f, 0.f, 0.f}, dIH = {0.f, 0.f, 0.f, 0.f};
    dRL = __builtin_amdgcn_mfma_f32_16x16x32_bf16(arL, bfr, dRL, 0, 0, 0);
    dIL = __builtin_amdgcn_mfma_f32_16x16x32_bf16(aiL, bfr, dIL, 0, 0, 0);
    dRH = __builtin_amdgcn_mfma_f32_16x16x32_bf16(arH, bfr, dRH, 0, 0, 0);
    dIH = __builtin_amdgcn_mfma_f32_16x16x32_bf16(aiH, bfr, dIH, 0, 0, 0);
    unsigned* ho = hs + (size_t)bl * 131072 + pxbase + pxt * 16 + ln;
#pragma unroll
    for (int j = 0; j < 4; ++j) {
      ho[(qd * 4 + j) * 4096] = pack_bf16(dRL[j], dIL[j]);
      ho[(16 + qd * 4 + j) * 4096] = pack_bf16(dRH[j], dIH[j]);
    }
  }
}

// ------------------------------------------------ MFMA zq (+ MLP tail blocks)
__global__ __launch_bounds__(256) void k_zq(
    const unsigned* __restrict__ hs, const short* __restrict__ zqA,
    float2* __restrict__ zq,
    const float* __restrict__ ctx, const float* __restrict__ listT,
    const float* __restrict__ plb, const float* __restrict__ dmod,
    const float* __restrict__ W1, const float* __restrict__ b1,
    const float* __restrict__ W2, const float* __restrict__ b2,
    const float* __restrict__ fscale,
    float2* __restrict__ lam, float* __restrict__ gam) {
  __shared__ unsigned HsB[4096];   // [s][w-chunks xor-swizzled], 16 KB
  __shared__ unsigned T2[2048];    // [q][s-chunks xor-swizzled], 8 KB
  __shared__ float mid_s[32];
  const int tid = threadIdx.x;
  if (blockIdx.x >= 2048) {        // ---- MLP -> lam/gam (ctx ready: mix done)
    int bl = blockIdx.x - 2048;
    float dt = listT[bl];
    if (tid < 32) {
      float a = b1[tid];
      for (int j = 0; j < 32; ++j) a += ctx[bl * 32 + j] * W1[j * 32 + tid];
      a += dt * W1[1024 + tid];
      mid_s[tid] = tanhf(a);
    }
    __syncthreads();
    float fs = fscale[0];
#pragma unroll
    for (int u = 0; u < 4; ++u) {
      int cr = u * 256 + tid;
      int col = cr * 2;
      float m0 = b2[col], m1 = b2[col + 1];
      for (int h = 0; h < 32; ++h) {
        float mh = mid_s[h];
        float2 w2 = *(const float2*)&W2[h * 2048 + col];
        m0 += mh * w2.x;
        m1 += mh * w2.y;
      }
      float dnu = fs * tanhf(m0);
      float dth = fs * tanhf(m1);
      float nub = expf(plb[cr] + dmod[cr]);
      float thb = expf(plb[1024 + cr] + dmod[1024 + cr]);
      float nut = fmaxf(nub * dt + dnu, 1e-6f);
      float tht = thb * dt + dth;
      float e = expf(-nut);
      float sa, ca;
      sincosf(tht, &sa, &ca);
      float g = sqrtf(fmaxf(1.f - expf(-2.f * nut), 1e-12f));
      int o = bl * 1024 + cr;
      lam[o] = make_float2(e * ca, e * sa);
      gam[o] = g;
    }
    return;
  }
  const int blc = blockIdx.x;
  const int c = blc & 31;
  const int lane = tid & 63, wv = tid >> 6;
  const int qd = lane >> 4, ln = lane & 15;
  const int mt = wv >> 1, nth = wv & 1;
  {
    const uint4* hp = (const uint4*)(hs + (size_t)blc * 4096);
#pragma unroll
    for (int it = 0; it < 4; ++it) {
      int i4 = tid + it * 256;
      uint4 v = hp[i4];
      int s = i4 >> 4, w4 = i4 & 15;
      *(uint4*)&HsB[s * 64 + ((w4 ^ (s & 15)) << 2)] = v;
    }
  }
  const short* zA = zqA + (size_t)c * 4 * 32 * 128;
  short8 a1[4], a2[4], a3[4], a4[4];
#pragma unroll
  for (int t = 0; t < 4; ++t) {
    int row = mt * 16 + ln;
    a1[t] = *(const short8*)(zA + (0 * 32 + row) * 128 + t * 32 + qd * 8);
    a2[t] = *(const short8*)(zA + (1 * 32 + row) * 128 + t * 32 + qd * 8);
    a3[t] = *(const short8*)(zA + (2 * 32 + row) * 128 + t * 32 + qd * 8);
    a4[t] = *(const short8*)(zA + (3 * 32 + row) * 128 + t * 32 + qd * 8);
  }
  __syncthreads();
#pragma unroll
  for (int nti = 0; nti < 2; ++nti) {
    int nt = nth * 2 + nti;
    int n = nt * 16 + ln;
    floatx4 accr = {0.f, 0.f, 0.f, 0.f}, acci = {0.f, 0.f, 0.f, 0.f};
#pragma unroll
    for (int t = 0; t < 4; ++t) {
      short8 b = *(const short8*)&HsB[n * 64 + (((4 * t + qd) ^ (n & 15)) << 2)];
      accr = __builtin_amdgcn_mfma_f32_16x16x32_bf16(a1[t], b, accr, 0, 0, 0);
      acci = __builtin_amdgcn_mfma_f32_16x16x32_bf16(a2[t], b, acci, 0, 0, 0);
    }
#pragma unroll
    for (int j = 0; j < 4; ++j) {
      int q = mt * 16 + qd * 4 + j;
      int s = n;
      T2[q * 64 + (((s >> 2) ^ (q & 15)) << 2) + (s & 3)] = pack_bf16(accr[j], acci[j]);
    }
  }
  __syncthreads();
  {
    const int mt2 = wv >> 1, nt2 = wv & 1;
    int n = nt2 * 16 + ln;
    floatx4 zr = {0.f, 0.f, 0.f, 0.f}, zi = {0.f, 0.f, 0.f, 0.f};
#pragma unroll
    for (int t = 0; t < 4; ++t) {
      short8 b = *(const short8*)&T2[n * 64 + (((4 * t + qd) ^ (n & 15)) << 2)];
      zr = __builtin_amdgcn_mfma_f32_16x16x32_bf16(a3[t], b, zr, 0, 0, 0);
      zi = __builtin_amdgcn_mfma_f32_16x16x32_bf16(a4[t], b, zi, 0, 0, 0);
    }
    float2* zo = zq + (size_t)blc * 1024;
#pragma unroll
    for (int j = 0; j < 4; ++j) {
      int r = mt2 * 16 + qd * 4 + j;
      zo[r * 32 + n] = make_float2(zr[j], zi[j]);
    }
  }
}

// --------------------- linear scan: 256 blocks, 1 chain/thread, prefetched
__global__ __launch_bounds__(256) void k_scan(const float2* __restrict__ lam,
                                              const float* __restrict__ gam,
                                              const float2* zin,
                                              float2* zout) {
  const int bc = blockIdx.x >> 2;
  const int b = bc >> 5, c = bc & 31;
  const int rq = (blockIdx.x & 3) * 256 + threadIdx.x;
  const int r = rq >> 5;
  float2 st = make_float2(0.f, 0.f);
  float2 v = zin[((size_t)(b * 32) * 32 + c) * 1024 + rq];
  float2 lm = lam[(b * 32) * 1024 + c * 32 + r];
  float g = gam[(b * 32) * 1024 + c * 32 + r];
  for (int t = 0; t < 32; ++t) {
    float2 nv, nlm;
    float ng;
    if (t < 31) {
      size_t zb2 = ((size_t)(b * 32 + t + 1) * 32 + c) * 1024;
      int pb2 = (b * 32 + t + 1) * 1024 + c * 32;
      nv = zin[zb2 + rq];
      nlm = lam[pb2 + r];
      ng = gam[pb2 + r];
    }
    float nr = lm.x * st.x - lm.y * st.y + g * v.x;
    float ni = lm.x * st.y + lm.y * st.x + g * v.y;
    st = make_float2(nr, ni);
    zout[((size_t)(b * 32 + t) * 32 + c) * 1024 + rq] = st;
    v = nv; lm = nlm; g = ng;
  }
}

// ------------------------------------------------------------ MFMA rec
__global__ __launch_bounds__(256) void k_rec(const float2* __restrict__ zs,
                                             const short* __restrict__ recA,
                                             const short* __restrict__ recB,
                                             unsigned* __restrict__ hsp) {
  __shared__ unsigned zB[1024];
  __shared__ unsigned P[2048];
  const int blc = blockIdx.x;
  const int c = blc & 31;
  const int tid = threadIdx.x;
  const int lane = tid & 63, wv = tid >> 6;
  const int qd = lane >> 4, ln = lane & 15;
  {
    const float2* zp = zs + (size_t)blc * 1024;
#pragma unroll
    for (int it = 0; it < 4; ++it) {
      int i = tid + it * 256;
      float2 v = zp[i];
      int r = i >> 5, q = i & 31;
      zB[q * 32 + (((r >> 2) ^ (q & 7)) << 2) + (r & 3)] = pack_bf16(v.x, v.y);
    }
  }
  const short* rA = recA + (size_t)c * 2 * 64 * 64;
  short8 a5[2], a6[2];
#pragma unroll
  for (int t = 0; t < 2; ++t) {
    int row = wv * 16 + ln;
    a5[t] = *(const short8*)(rA + (0 * 64 + row) * 64 + t * 32 + qd * 8);
    a6[t] = *(const short8*)(rA + (1 * 64 + row) * 64 + t * 32 + qd * 8);
  }
  __syncthreads();
#pragma unroll
  for (int nt = 0; nt < 2; ++nt) {
    int n = nt * 16 + ln;
    floatx4 pr = {0.f, 0.f, 0.f, 0.f}, pi = {0.f, 0.f, 0.f, 0.f};
#pragma unroll
    for (int t = 0; t < 2; ++t) {
      short8 b = *(const short8*)&zB[n * 32 + (((4 * t + qd) ^ (n & 7)) << 2)];
      pr = __builtin_amdgcn_mfma_f32_16x16x32_bf16(a5[t], b, pr, 0, 0, 0);
      pi = __builtin_amdgcn_mfma_f32_16x16x32_bf16(a6[t], b, pi, 0, 0, 0);
    }
#pragma unroll
    for (int j = 0; j < 4; ++j) {
      int s = wv * 16 + qd * 4 + j;
      int q = n;
      P[s * 32 + (((q >> 2) ^ (s & 7)) << 2) + (q & 3)] = pack_bf16(pr[j], pi[j]);
    }
  }
  __syncthreads();
  const short* rB = recB + (size_t)c * 2 * 64 * 64;
  short8 pa[2];
#pragma unroll
  for (int t = 0; t < 2; ++t) {
    int row = wv * 16 + ln;
    pa[t] = *(const short8*)&P[row * 32 + (((4 * t + qd) ^ (row & 7)) << 2)];
  }
#pragma unroll
  for (int nt = 0; nt < 4; ++nt) {
    int n = nt * 16 + ln;
    floatx4 hr = {0.f, 0.f, 0.f, 0.f}, hi = {0.f, 0.f, 0.f, 0.f};
#pragma unroll
    for (int t = 0; t < 2; ++t) {
      short8 b5 = *(const short8*)(rB + (0 * 64 + n) * 64 + t * 32 + qd * 8);
      short8 b6 = *(const short8*)(rB + (1 * 64 + n) * 64 + t * 32 + qd * 8);
      hr = __builtin_amdgcn_mfma_f32_16x16x32_bf16(pa[t], b5, hr, 0, 0, 0);
      hi = __builtin_amdgcn_mfma_f32_16x16x32_bf16(pa[t], b6, hi, 0, 0, 0);
    }
    unsigned* ho = hsp + (size_t)blc * 4096;
#pragma unroll
    for (int j = 0; j < 4; ++j) {
      int s = wv * 16 + qd * 4 + j;
      ho[s * 64 + n] = pack_bf16(hr[j], hi[j]);
    }
  }
}

// ------------------------------------------------------------ MFMA 3x3 conv
// 4-row slabs; each wave owns one x-quarter and BOTH co-groups (2 MFMAs per
// A-read -> ds_read halved). Output bf16.
__global__ __launch_bounds__(256, 2) void k_conv(
    const unsigned* __restrict__ hsp, const short* __restrict__ Wtb,
    unsigned short* __restrict__ convout, float2* __restrict__ stats) {
  __shared__ unsigned lds_in[6 * 66 * 32];   // 50,688 B
  const int bl = blockIdx.x >> 4;
  const int slab = blockIdx.x & 15;
  const int y0 = slab * 4;
  const int tid = threadIdx.x;
  for (int i = tid; i < 384; i += 256) {     // zero x-border cells
    int ci = i & 31, j = i >> 5;
    int yi = j >> 1, xi = (j & 1) ? 65 : 0;
    int slot = (ci >> 2) ^ (xi & 7);
    lds_in[(yi * 66 + xi) * 32 + slot * 4 + (ci & 3)] = 0u;
  }
#pragma unroll
  for (int t = 0; t < 12; ++t) {             // interior staging
    int i = t * 256 + tid;
    int ci = i & 31;
    int j = i >> 5;
    int yi = j >> 4, x4 = j & 15;
    int y = y0 + yi - 1;
    uint4 v = make_uint4(0u, 0u, 0u, 0u);
    if ((unsigned)y < 64u)
      v = *(const uint4*)(hsp + (((size_t)bl * 32 + ci) * 64 + y) * 64 + x4 * 4);
    int xb = 1 + x4 * 4;
#pragma unroll
    for (int jj = 0; jj < 4; ++jj) {
      int xi = xb + jj;
      int slot = (ci >> 2) ^ (xi & 7);
      lds_in[(yi * 66 + xi) * 32 + slot * 4 + (ci & 3)] =
          ((const unsigned*)&v)[jj];
    }
  }
  const int lane = tid & 63;
  const int wv = tid >> 6;
  const int co = lane & 15;
  const int qd = lane >> 4;
  short8 bL[18], bH[18];
  {
    const short* wpL = Wtb + (co * 9) * 64 + qd * 8;
    const short* wpH = Wtb + ((co + 16) * 9) * 64 + qd * 8;
#pragma unroll
    for (int tap = 0; tap < 9; ++tap)
#pragma unroll
      for (int kk = 0; kk < 2; ++kk) {
        bL[tap * 2 + kk] = *(const short8*)(wpL + tap * 64 + kk * 32);
        bH[tap * 2 + kk] = *(const short8*)(wpH + tap * 64 + kk * 32);
      }
  }
  __syncthreads();
  float sL = 0.f, s2L = 0.f, sH = 0.f, s2H = 0.f;
  const int x0 = wv * 16;
  const int xl = lane & 15;
  for (int ry = 0; ry < 4; ++ry) {
    floatx4 aL = {0.f, 0.f, 0.f, 0.f}, aH = {0.f, 0.f, 0.f, 0.f};
#pragma unroll
    for (int tap = 0; tap < 9; ++tap) {
      int dy = tap / 3, dx = tap - dy * 3;
      int yi = ry + dy;
      int xi = x0 + xl + dx;
#pragma unroll
      for (int kk = 0; kk < 2; ++kk) {
        int slot = ((kk << 2) | qd) ^ (xi & 7);
        const short8 a =
            *(const short8*)&lds_in[(yi * 66 + xi) * 32 + slot * 4];
        aL = __builtin_amdgcn_mfma_f32_16x16x32_bf16(a, bL[tap * 2 + kk], aL, 0, 0, 0);
        aH = __builtin_amdgcn_mfma_f32_16x16x32_bf16(a, bH[tap * 2 + kk], aH, 0, 0, 0);
      }
    }
    size_t goL = (((size_t)bl * 32 + co) * 64 + (y0 + ry)) * 64 + x0 + qd * 4;
    size_t goH = goL + (size_t)16 * 4096;
    *(uint2*)(convout + goL) =
        make_uint2(pack_bf16(aL[0], aL[1]), pack_bf16(aL[2], aL[3]));
    *(uint2*)(convout + goH) =
        make_uint2(pack_bf16(aH[0], aH[1]), pack_bf16(aH[2], aH[3]));
#pragma unroll
    for (int j = 0; j < 4; ++j) {
      sL += aL[j]; s2L += aL[j] * aL[j];
      sH += aH[j]; s2H += aH[j] * aH[j];
    }
  }
  sL += __shfl_down(sL, 32, 64);  s2L += __shfl_down(s2L, 32, 64);
  sH += __shfl_down(sH, 32, 64);  s2H += __shfl_down(s2H, 32, 64);
  sL += __shfl_down(sL, 16, 64);  s2L += __shfl_down(s2L, 16, 64);
  sH += __shfl_down(sH, 16, 64);  s2H += __shfl_down(s2H, 16, 64);
  if (lane < 16) {
    stats[((size_t)bl * 32 + lane) * 64 + slab * 4 + wv] = make_float2(sL, s2L);
    stats[((size_t)bl * 32 + 16 + lane) * 64 + slab * 4 + wv] =
        make_float2(sH, s2H);
  }
}

// -------------------------------------------------------- LN + residual out
__global__ __launch_bounds__(256) void k_ln(
    const unsigned short* __restrict__ convout,
    const float2* __restrict__ stats, const float* __restrict__ x,
    const float* __restrict__ ln_w, const float* __restrict__ ln_b,
    float* __restrict__ out) {
  const int blc = blockIdx.x;
  const int tid = threadIdx.x;
  __shared__ float sh_mu, sh_rs;
  if (tid < 64) {
    float2 v = stats[(size_t)blc * 64 + tid];
    float s = v.x, s2 = v.y;
#pragma unroll
    for (int o = 32; o > 0; o >>= 1) {
      s += __shfl_down(s, o, 64);
      s2 += __shfl_down(s2, o, 64);
    }
    if (tid == 0) {
      float mu = s * (1.f / 4096.f);
      float var = s2 * (1.f / 4096.f) - mu * mu;
      sh_mu = mu;
      sh_rs = rsqrtf(var + 1e-5f);
    }
  }
  __syncthreads();
  float mu = sh_mu, rs = sh_rs;
  const uint2* cp = (const uint2*)(convout + (size_t)blc * 4096);
  const float4* xp = (const float4*)(x + (size_t)blc * 4096);
  const float4* lwp = (const float4*)ln_w;
  const float4* lbp = (const float4*)ln_b;
  float4* op = (float4*)(out + (size_t)blc * 4096);
#pragma unroll
  for (int k = 0; k < 4; ++k) {
    int i = tid + k * 256;
    uint2 cv = cp[i];
    float4 xv = xp[i], lw = lwp[i], lb = lbp[i];
    float c0 = __uint_as_float(cv.x << 16);
    float c1 = __uint_as_float(cv.x & 0xFFFF0000u);
    float c2 = __uint_as_float(cv.y << 16);
    float c3 = __uint_as_float(cv.y & 0xFFFF0000u);
    float4 o;
    o.x = xv.x + (c0 - mu) * rs * lw.x + lb.x;
    o.y = xv.y + (c1 - mu) * rs * lw.y + lb.y;
    o.z = xv.z + (c2 - mu) * rs * lw.z + lb.z;
    o.w = xv.w + (c3 - mu) * rs * lw.w + lb.w;
    op[i] = o;
  }
}

// ------------------------------------------------------------------- launch
extern "C" void kernel_launch(void* const* d_in, const int* in_sizes, int n_in,
                              void* d_out, int out_size, void* d_ws,
                              size_t ws_size, hipStream_t stream) {
  const float* x       = (const float*)d_in[0];
  const float* listT   = (const float*)d_in[1];
  const float* plb     = (const float*)d_in[2];
  const float* dmod    = (const float*)d_in[3];
  const float* fm_W1   = (const float*)d_in[4];
  const float* fm_b1   = (const float*)d_in[5];
  const float* fm_W2   = (const float*)d_in[6];
  const float* fm_b2   = (const float*)d_in[7];
  const float* fscale  = (const float*)d_in[8];
  const float* U_re    = (const float*)d_in[9];
  const float* U_im    = (const float*)d_in[10];
  const float* V_re    = (const float*)d_in[11];
  const float* V_im    = (const float*)d_in[12];
  const float* pW_re   = (const float*)d_in[13];
  const float* pW_im   = (const float*)d_in[14];
  // d_in[15..16] pb_re/pb_im: cropped out, no effect
  const float* convr_w = (const float*)d_in[17];
  // convr_b/convi_b/projc_b (18,20,22): constant over [S,W] -> cancel in LN
  const float* convi_w = (const float*)d_in[19];
  const float* projc_w = (const float*)d_in[21];
  const float* ln_w    = (const float*)d_in[23];
  const float* ln_b    = (const float*)d_in[24];
  float* out = (float*)d_out;

  float* wsf = (float*)d_ws;
  // R0a [0, 8388608): hs (u32 packed bf16) -> later hsp (alias)
  unsigned* hs  = (unsigned*)wsf;
  unsigned* hsp = (unsigned*)wsf;
  // R0b [8388608, 16777216): coeff mats (dead before conv), then convout(bf16)+stats
  unsigned* zqAp  = (unsigned*)(wsf + 8388608);           // 262144 u32
  unsigned* recAp = (unsigned*)(wsf + 8388608 + 262144);  // 131072 u32
  unsigned* recBp = (unsigned*)(wsf + 8388608 + 393216);  // 131072 u32
  unsigned short* convout = (unsigned short*)(wsf + 8388608);  // 8388608 u16
  float2*   stats = (float2*)(wsf + 12582912);            // 131072 float2
  float2*   zq  = (float2*)(wsf + 16777216);              // 4,194,304 fl
  size_t off = 16777216 + 4194304;
  float2* zs = (float2*)(wsf + off);
  size_t need_with_zs = (size_t)(off + 4194304 + 470016) * 4;
  bool sep = ws_size >= need_with_zs;
  if (sep) off += 4194304; else zs = zq;
  float2*   lam  = (float2*)(wsf + off);                  // 131,072 fl
  float*    gam  = wsf + off + 131072;                    // 65,536 fl
  float*    ctx  = wsf + off + 458752;                    // 2,048 fl
  unsigned* Wtb  = (unsigned*)(wsf + off + 460800);       // 9,216 u32

  k_prep<<<2085, 256, 0, stream>>>(U_re, U_im, V_re, V_im, projc_w,
                                   convr_w, convi_w, zqAp, recAp, recBp,
                                   Wtb, ctx);
  k_mix<<<512, 256, 0, stream>>>(x, pW_re, pW_im, hs, ctx);
  k_zq<<<2112, 256, 0, stream>>>(hs, (const short*)zqAp, zq, ctx, listT, plb,
                                 dmod, fm_W1, fm_b1, fm_W2, fm_b2, fscale,
                                 lam, gam);
  k_scan<<<256, 256, 0, stream>>>(lam, gam, zq, zs);
  k_rec<<<2048, 256, 0, stream>>>(zs, (const short*)recAp, (const short*)recBp, hsp);
  k_conv<<<1024, 256, 0, stream>>>(hsp, (const short*)Wtb, convout, stats);
  k_ln<<<2048, 256, 0, stream>>>(convout, stats, x, ln_w, ln_b, out);
}